// Round 9
// baseline (965.889 us; speedup 1.0000x reference)
//
#include <hip/hip_runtime.h>
#include <hip/hip_bf16.h>

#define DIM   1024
#define NTOK  2048
#define HEADS 16
#define FFH   2730
#define FF2   5460
#define FFHP  2752   /* FFH padded to x64 */
#define FFNP  2816   /* FFH padded to x128 */
#define DEPTH 4
#define EPS_RMS 1.1920929e-07f
#define QK_SCALE 0.125f

typedef __attribute__((ext_vector_type(8))) short bf16x8;
typedef __attribute__((ext_vector_type(4))) float f32x4;

__device__ __forceinline__ unsigned short f2bf(float x) {
    unsigned u = __float_as_uint(x);
    u += 0x7fffu + ((u >> 16) & 1);          // RNE
    return (unsigned short)(u >> 16);
}
__device__ __forceinline__ unsigned pk2(float a, float b) {
    unsigned ua = __float_as_uint(a); ua += 0x7fffu + ((ua >> 16) & 1);
    unsigned ub = __float_as_uint(b); ub += 0x7fffu + ((ub >> 16) & 1);
    return (ua >> 16) | (ub & 0xffff0000u);
}
// async global->LDS, 16B per lane; dest must be wave-uniform base + lane*16
__device__ __forceinline__ void gll16(const void* g, void* l) {
    __builtin_amdgcn_global_load_lds(
        (const __attribute__((address_space(1))) void*)g,
        (__attribute__((address_space(3))) void*)l, 16, 0, 0);
}

// ---------------- RMSNorm (layer-0 attn norm): fp32 out + bf16 out ---------------
__global__ void rmsnorm_k(const float* __restrict__ in, const float* __restrict__ w,
                          float* __restrict__ out, unsigned short* __restrict__ outbf) {
    int row = blockIdx.x;
    int tid = threadIdx.x;
    const float4* in4 = (const float4*)(in + (size_t)row * DIM);
    float4 v = in4[tid];
    float ss = v.x * v.x + v.y * v.y + v.z * v.z + v.w * v.w;
    #pragma unroll
    for (int off = 32; off > 0; off >>= 1) ss += __shfl_down(ss, off);
    __shared__ float lds[4];
    __shared__ float stot;
    int wid = tid >> 6, lane = tid & 63;
    if (lane == 0) lds[wid] = ss;
    __syncthreads();
    if (tid == 0) stot = lds[0] + lds[1] + lds[2] + lds[3];
    __syncthreads();
    float inv = 1.0f / sqrtf(stot * (1.0f / DIM) + EPS_RMS);
    const float4* w4 = (const float4*)w;
    float4 wv = w4[tid];
    float4 o;
    o.x = v.x * inv * wv.x; o.y = v.y * inv * wv.y;
    o.z = v.z * inv * wv.z; o.w = v.w * inv * wv.w;
    ((float4*)(out + (size_t)row * DIM))[tid] = o;
    if (outbf) {
        unsigned long long p = (unsigned long long)pk2(o.x, o.y)
                             | ((unsigned long long)pk2(o.z, o.w) << 32);
        ((unsigned long long*)(outbf + (size_t)row * DIM))[tid] = p;
    }
}

// ---------------- fused residual-reduce + RMSNorm --------------------------------
template<int S>
__global__ void rmsnorm_red_k(const float* __restrict__ X, const float* __restrict__ P,
                              const float* __restrict__ bias, const float* __restrict__ w,
                              float* __restrict__ Xout, float* __restrict__ Hf,
                              unsigned short* __restrict__ Hbf) {
    int row = blockIdx.x;
    int tid = threadIdx.x;
    float4 x = ((const float4*)(X + (size_t)row * DIM))[tid];
    #pragma unroll
    for (int s = 0; s < S; s++) {
        float4 p = ((const float4*)(P + (size_t)s * NTOK * DIM + (size_t)row * DIM))[tid];
        x.x += p.x; x.y += p.y; x.z += p.z; x.w += p.w;
    }
    if (bias) {
        float4 b = ((const float4*)bias)[tid];
        x.x += b.x; x.y += b.y; x.z += b.z; x.w += b.w;
    }
    float ss = x.x * x.x + x.y * x.y + x.z * x.z + x.w * x.w;
    #pragma unroll
    for (int off = 32; off > 0; off >>= 1) ss += __shfl_down(ss, off);
    __shared__ float lds[4];
    __shared__ float stot;
    int wid = tid >> 6, lane = tid & 63;
    if (lane == 0) lds[wid] = ss;
    __syncthreads();
    if (tid == 0) stot = lds[0] + lds[1] + lds[2] + lds[3];
    __syncthreads();
    float inv = 1.0f / sqrtf(stot * (1.0f / DIM) + EPS_RMS);
    if (Xout) ((float4*)(Xout + (size_t)row * DIM))[tid] = x;
    float4 wv = ((const float4*)w)[tid];
    float4 o;
    o.x = x.x * inv * wv.x; o.y = x.y * inv * wv.y;
    o.z = x.z * inv * wv.z; o.w = x.w * inv * wv.w;
    if (Hf) ((float4*)(Hf + (size_t)row * DIM))[tid] = o;
    if (Hbf) {
        unsigned long long p = (unsigned long long)pk2(o.x, o.y)
                             | ((unsigned long long)pk2(o.z, o.w) << 32);
        ((unsigned long long*)(Hbf + (size_t)row * DIM))[tid] = p;
    }
}

// ---------------- weight transpose+convert: W fp32 [Ksrc][stride] -> bf16 [Np][Kp]
__global__ __launch_bounds__(256) void wconv_k(
        const float* __restrict__ W, short* __restrict__ out,
        int Ksrc, int Nsrc, int colOfs, int rowStride, int Kp, int Np) {
    __shared__ float tile[64][65];
    int k0 = blockIdx.y * 64, n0 = blockIdx.x * 64;
    int tid = threadIdx.x;
    int c = tid & 63;
    #pragma unroll
    for (int kk4 = 0; kk4 < 16; kk4++) {
        int kk = kk4 * 4 + (tid >> 6);
        int gk = k0 + kk, gn = n0 + c;
        float v = 0.f;
        if (gk < Ksrc && gn < Nsrc) v = W[(size_t)gk * rowStride + colOfs + gn];
        tile[kk][c] = v;
    }
    __syncthreads();
    #pragma unroll
    for (int it = 0; it < 4; it++) {
        int flat = tid + 256 * it;
        int nn = flat >> 4, kg = (flat & 15) * 4;
        int gn = n0 + nn, gk = k0 + kg;
        if (gn < Np && gk < Kp) {
            short4 s;
            s.x = (short)f2bf(tile[kg + 0][nn]);
            s.y = (short)f2bf(tile[kg + 1][nn]);
            s.z = (short)f2bf(tile[kg + 2][nn]);
            s.w = (short)f2bf(tile[kg + 3][nn]);
            *(short4*)(out + (size_t)gn * Kp + gk) = s;
        }
    }
}

// ---------------- bf16 MFMA GEMM, split-K, 2-phase pipelined ---------------------
// 128x128 tile, BK=64, 4 waves (2x2). Double-buffered LDS (64KB, 2 blocks/CU);
// next K-tile's global_load_lds issued BEFORE current tile's MFMA so the async
// loads land under compute; __syncthreads (vmcnt(0)+barrier) once per K-step.
// XOR swizzle folded into the GLOBAL source column; fragment reads swizzled.
template<int SPLITK>
__global__ __launch_bounds__(256, 2) void gemm_splitk_k(
        const short* __restrict__ A, const short* __restrict__ Bt,
        float* __restrict__ Cpart, int N, int Kp) {
    __shared__ __align__(16) short As[2][128 * 64];
    __shared__ __align__(16) short Bs[2][128 * 64];
    int tid = threadIdx.x;
    int wv = tid >> 6, ln = tid & 63, g = ln >> 4, t = ln & 15;
    int wr = wv >> 1, wc = wv & 1;
    int rowBase = blockIdx.y * 128, colBase = blockIdx.x * 128;
    float* Cz = Cpart + (size_t)blockIdx.z * NTOK * N;
    f32x4 acc[4][4] = {};
    int KT = Kp >> 6;
    int kt0 = (KT * blockIdx.z) / SPLITK, kt1 = (KT * (blockIdx.z + 1)) / SPLITK;

    auto STAGE = [&](int buf, int kt) {
        int k0 = kt * 64;
        #pragma unroll
        for (int i = 0; i < 4; i++) {
            int idx = tid + 256 * i;
            int r = idx >> 3, c8 = idx & 7;
            int cs = (c8 ^ (r & 7)) * 8;
            gll16(A + (size_t)(rowBase + r) * Kp + k0 + cs, (char*)As[buf] + idx * 16);
            gll16(Bt + (size_t)(colBase + r) * Kp + k0 + cs, (char*)Bs[buf] + idx * 16);
        }
    };
    STAGE(0, kt0);
    __syncthreads();
    int cur = 0;
    for (int kt = kt0; kt < kt1; kt++) {
        if (kt + 1 < kt1) STAGE(cur ^ 1, kt + 1);
        #pragma unroll
        for (int ks = 0; ks < 2; ks++) {
            bf16x8 af[4], bf[4];
            #pragma unroll
            for (int mi = 0; mi < 4; mi++) {
                int row = wr * 64 + mi * 16 + t;
                int kb = (ks * 64 + g * 16) ^ ((row & 7) << 4);
                af[mi] = *(const bf16x8*)((const char*)As[cur] + row * 128 + kb);
            }
            #pragma unroll
            for (int ni = 0; ni < 4; ni++) {
                int row = wc * 64 + ni * 16 + t;
                int kb = (ks * 64 + g * 16) ^ ((row & 7) << 4);
                bf[ni] = *(const bf16x8*)((const char*)Bs[cur] + row * 128 + kb);
            }
            #pragma unroll
            for (int mi = 0; mi < 4; mi++)
                #pragma unroll
                for (int ni = 0; ni < 4; ni++)
                    acc[mi][ni] = __builtin_amdgcn_mfma_f32_16x16x32_bf16(
                        af[mi], bf[ni], acc[mi][ni], 0, 0, 0);
        }
        __syncthreads();
        cur ^= 1;
    }
    #pragma unroll
    for (int mi = 0; mi < 4; mi++)
        #pragma unroll
        for (int ni = 0; ni < 4; ni++) {
            int col = colBase + wc * 64 + ni * 16 + t;
            #pragma unroll
            for (int r = 0; r < 4; r++) {
                int row = rowBase + wr * 64 + mi * 16 + g * 4 + r;
                Cz[(size_t)row * N + col] = acc[mi][ni][r];
            }
        }
}

// ---------------- SwiGLU fused GEMM, 2-phase: 128x64 tile ------------------------
// act = (h@Wa+ba)*gelu(h@Wg+bg) -> bf16. 4 waves (2x2), per-wave 64x32 out,
// double-buffered (A 2x16KB + B1/B2 2x8KB = 64KB, 2 blocks/CU), grid (43,16).
__global__ __launch_bounds__(256, 2) void gemm_swiglu_k(
        const short* __restrict__ A, const short* __restrict__ Ba,
        const short* __restrict__ Bg, const float* __restrict__ biasIn,
        unsigned short* __restrict__ actbf) {
    __shared__ __align__(16) short As[2][128 * 64];
    __shared__ __align__(16) short B1[2][64 * 64];
    __shared__ __align__(16) short B2[2][64 * 64];
    int tid = threadIdx.x;
    int wv = tid >> 6, ln = tid & 63, g = ln >> 4, t = ln & 15;
    int wr = wv >> 1, wc = wv & 1;
    int rowBase = blockIdx.y * 128, colBase = blockIdx.x * 64;
    f32x4 acca[4][2] = {};
    f32x4 accg[4][2] = {};

    auto STAGE = [&](int buf, int kt) {
        int k0 = kt * 64;
        #pragma unroll
        for (int i = 0; i < 4; i++) {
            int idx = tid + 256 * i;
            int r = idx >> 3, c8 = idx & 7;
            int cs = (c8 ^ (r & 7)) * 8;
            gll16(A + (size_t)(rowBase + r) * 1024 + k0 + cs, (char*)As[buf] + idx * 16);
        }
        #pragma unroll
        for (int i = 0; i < 2; i++) {
            int idx = tid + 256 * i;
            int r = idx >> 3, c8 = idx & 7;
            int cs = (c8 ^ (r & 7)) * 8;
            gll16(Ba + (size_t)(colBase + r) * 1024 + k0 + cs, (char*)B1[buf] + idx * 16);
            gll16(Bg + (size_t)(colBase + r) * 1024 + k0 + cs, (char*)B2[buf] + idx * 16);
        }
    };
    STAGE(0, 0);
    __syncthreads();
    int cur = 0;
    for (int kt = 0; kt < 16; kt++) {
        if (kt + 1 < 16) STAGE(cur ^ 1, kt + 1);
        #pragma unroll
        for (int ks = 0; ks < 2; ks++) {
            bf16x8 af[4], b1f[2], b2f[2];
            #pragma unroll
            for (int mi = 0; mi < 4; mi++) {
                int row = wr * 64 + mi * 16 + t;
                int kb = (ks * 64 + g * 16) ^ ((row & 7) << 4);
                af[mi] = *(const bf16x8*)((const char*)As[cur] + row * 128 + kb);
            }
            #pragma unroll
            for (int ni = 0; ni < 2; ni++) {
                int row = wc * 32 + ni * 16 + t;
                int kb = (ks * 64 + g * 16) ^ ((row & 7) << 4);
                b1f[ni] = *(const bf16x8*)((const char*)B1[cur] + row * 128 + kb);
                b2f[ni] = *(const bf16x8*)((const char*)B2[cur] + row * 128 + kb);
            }
            #pragma unroll
            for (int mi = 0; mi < 4; mi++)
                #pragma unroll
                for (int ni = 0; ni < 2; ni++) {
                    acca[mi][ni] = __builtin_amdgcn_mfma_f32_16x16x32_bf16(
                        af[mi], b1f[ni], acca[mi][ni], 0, 0, 0);
                    accg[mi][ni] = __builtin_amdgcn_mfma_f32_16x16x32_bf16(
                        af[mi], b2f[ni], accg[mi][ni], 0, 0, 0);
                }
        }
        __syncthreads();
        cur ^= 1;
    }
    const float rs2 = 0.70710678118654752f;
    #pragma unroll
    for (int mi = 0; mi < 4; mi++)
        #pragma unroll
        for (int ni = 0; ni < 2; ni++) {
            int col = colBase + wc * 32 + ni * 16 + t;
            float ba = (col < FFH) ? biasIn[col] : 0.f;
            float bg = (col < FFH) ? biasIn[FFH + col] : 0.f;
            #pragma unroll
            for (int r = 0; r < 4; r++) {
                int row = rowBase + wr * 64 + mi * 16 + g * 4 + r;
                unsigned short outv = 0;
                if (col < FFH) {
                    float a_ = acca[mi][ni][r] + ba;
                    float g_ = accg[mi][ni][r] + bg;
                    float gel = 0.5f * g_ * (1.0f + erff(g_ * rs2));
                    outv = f2bf(a_ * gel);
                }
                actbf[(size_t)row * FFHP + col] = outv;
            }
        }
}

// ---------------- mix = sigmoid(h @ w_mix + b_mix) -------------------------------
__global__ void mix_k(const float* __restrict__ h, const float* __restrict__ wm,
                      const float* __restrict__ bm, float* __restrict__ mix) {
    int row = blockIdx.x;
    int tid = threadIdx.x;
    int hh = tid & 15, kl = tid >> 4;
    const float* hr = h + (size_t)row * DIM;
    float p = 0.f;
    for (int j = 0; j < 64; j++) {
        int k = kl + 16 * j;
        p += hr[k] * wm[k * 16 + hh];
    }
    __shared__ float lds[256];
    lds[tid] = p;
    __syncthreads();
    if (tid < 16) {
        float s = 0.f;
        #pragma unroll
        for (int k2 = 0; k2 < 16; k2++) s += lds[k2 * 16 + tid];
        s += bm[tid];
        mix[row * HEADS + tid] = 1.0f / (1.0f + expf(-s));
    }
}

// ---------------- RoPE on q,k (sums 2 qkv partials) -> bf16 ----------------------
__global__ void rope_lerp_k(const float* __restrict__ P0, const float* __restrict__ P1,
                            unsigned short* __restrict__ qbf,
                            unsigned short* __restrict__ kbf) {
    int row = blockIdx.x;
    int tid = threadIdx.x;
    const float* qr0 = P0 + (size_t)row * 3072;
    const float* qr1 = P1 + (size_t)row * 3072;
    #pragma unroll
    for (int it = 0; it < 2; it++) {
        int p = tid + 256 * it;
        int hh = p >> 5, pr = p & 31;
        float freq = expf(-(float)pr * (1.0f / 32.0f) * 9.2103403719762f);
        float ang = (float)row * freq;
        float s, c;
        sincosf(ang, &s, &c);
        int base = hh * 64 + pr * 2;
        float q0 = qr0[base] + qr1[base];
        float q1 = qr0[base + 1] + qr1[base + 1];
        float qa = q0 * c - q1 * s, qb = q1 * c + q0 * s;
        *(unsigned*)(qbf + (size_t)row * DIM + base) = pk2(qa * QK_SCALE, qb * QK_SCALE);
        float k0 = qr0[1024 + base] + qr1[1024 + base];
        float k1 = qr0[1024 + base + 1] + qr1[1024 + base + 1];
        *(unsigned*)(kbf + (size_t)row * DIM + base) = pk2(k0 * c - k1 * s, k1 * c + k0 * s);
    }
}

// ---------------- V: sum partials + value-residual lerp + transpose -> Vtg -------
__global__ __launch_bounds__(256) void vtrans_k(
        const float* __restrict__ P0, const float* __restrict__ P1,
        float* __restrict__ fv, const float* __restrict__ mix,
        unsigned short* __restrict__ vtg, int layer) {
    __shared__ __align__(16) short T[64 * 64];
    int h = blockIdx.x, n0 = blockIdx.y * 64;
    int tid = threadIdx.x;
    #pragma unroll
    for (int it = 0; it < 2; it++) {
        int flat = tid + 256 * it;
        int n = flat >> 3, d0 = (flat & 7) * 8;
        int row = n0 + n;
        size_t off = (size_t)row * 3072 + 2048 + h * 64 + d0;
        float4 a0 = *(const float4*)(P0 + off);
        float4 a1 = *(const float4*)(P0 + off + 4);
        float4 b0 = *(const float4*)(P1 + off);
        float4 b1 = *(const float4*)(P1 + off + 4);
        float vals[8] = {a0.x + b0.x, a0.y + b0.y, a0.z + b0.z, a0.w + b0.w,
                         a1.x + b1.x, a1.y + b1.y, a1.z + b1.z, a1.w + b1.w};
        float* fvp = fv + (size_t)row * DIM + h * 64 + d0;
        if (layer == 0) {
            *(float4*)fvp = make_float4(vals[0], vals[1], vals[2], vals[3]);
            *(float4*)(fvp + 4) = make_float4(vals[4], vals[5], vals[6], vals[7]);
        } else {
            float m = mix[row * HEADS + h];
            float4 f0 = *(const float4*)fvp;
            float4 f1 = *(const float4*)(fvp + 4);
            float fvv[8] = {f0.x, f0.y, f0.z, f0.w, f1.x, f1.y, f1.z, f1.w};
            #pragma unroll
            for (int e = 0; e < 8; e++) vals[e] += m * (fvv[e] - vals[e]);
        }
        #pragma unroll
        for (int e = 0; e < 8; e++) {
            int d = d0 + e;
            *(short*)((char*)T + d * 128 + ((2 * n) ^ ((d & 7) << 4))) = (short)f2bf(vals[e]);
        }
    }
    __syncthreads();
    #pragma unroll
    for (int it = 0; it < 2; it++) {
        int flat = tid + 256 * it;
        int d = flat >> 3, nn0 = (flat & 7) * 8;
        uint4 v = *(const uint4*)((const char*)T + d * 128 + ((2 * nn0) ^ ((d & 7) << 4)));
        *(uint4*)(vtg + (size_t)(h * 64 + d) * NTOK + n0 + nn0) = v;
    }
}

// ---------------- MFMA flash attention: balanced paired q-tiles ------------------
__global__ __launch_bounds__(256, 2) void attn_mfma_k(
        const unsigned short* __restrict__ Qbf, const unsigned short* __restrict__ Kbf,
        const unsigned short* __restrict__ Vtg, unsigned short* __restrict__ obf) {
    const int h = blockIdx.x, pri = blockIdx.y;
    const int tid = threadIdx.x;
    const int wv = tid >> 6, ln = tid & 63, g = ln >> 4, t = ln & 15;
    __shared__ __align__(16) short KsB[2][64 * 64];
    __shared__ __align__(16) short VtB[2][64 * 64];
    __shared__ __align__(16) short Plds[4 * 16 * 64];
    char* pw = (char*)(Plds + wv * 1024);

    const int sr = ln >> 3;
    const int scol = (ln & 7) ^ sr;                 // swizzle on global source
    const int sbyte0 = (wv * 16 + sr) * 128 + (ln & 7) * 16;
    const int sbyte1 = sbyte0 + 8 * 128;
    const unsigned short* kgl0 = Kbf + (size_t)(wv * 16 + sr) * DIM + h * 64 + scol * 8;
    const unsigned short* kgl1 = kgl0 + 8 * DIM;
    const unsigned short* vgl0 = Vtg + (size_t)(h * 64 + wv * 16 + sr) * NTOK + scol * 8;
    const unsigned short* vgl1 = vgl0 + 8 * NTOK;

    for (int ph = 0; ph < 2; ph++) {
        const int j = ph ? (31 - pri) : pri;
        const int nch = ((j >> 1) + 1) * 2;
        const int qbase = j * 64;
        const unsigned short* qrow = Qbf + (size_t)(qbase + wv * 16 + t) * DIM + h * 64;
        bf16x8 qf0 = *(const bf16x8*)(qrow + 8 * g);
        bf16x8 qf1 = *(const bf16x8*)(qrow + 32 + 8 * g);
        f32x4 acc_o[4] = {};
        float mrun = -3.0e38f, lrun = 0.f;
        uint4 rk0 = *(const uint4*)kgl0;
        uint4 rk1 = *(const uint4*)kgl1;
        uint4 rv0 = *(const uint4*)vgl0;
        uint4 rv1 = *(const uint4*)vgl1;
        for (int kc = 0; kc < nch; kc++) {
            const int cur = kc & 1;
            *(uint4*)((char*)KsB[cur] + sbyte0) = rk0;
            *(uint4*)((char*)KsB[cur] + sbyte1) = rk1;
            *(uint4*)((char*)VtB[cur] + sbyte0) = rv0;
            *(uint4*)((char*)VtB[cur] + sbyte1) = rv1;
            if (kc + 1 < nch) {
                rk0 = *(const uint4*)(kgl0 + (size_t)(kc + 1) * 64 * DIM);
                rk1 = *(const uint4*)(kgl1 + (size_t)(kc + 1) * 64 * DIM);
                rv0 = *(const uint4*)(vgl0 + (kc + 1) * 64);
                rv1 = *(const uint4*)(vgl1 + (kc + 1) * 64);
            }
            __syncthreads();
            const char* Kc = (const char*)KsB[cur];
            const char* Vc = (const char*)VtB[cur];
            f32x4 accs[4] = {};
            #pragma unroll
            for (int kf = 0; kf < 4; kf++) {
                int row = kf * 16 + t;
                int kb0 = (g * 16) ^ ((row & 7) << 4);
                int kb1 = (64 + g * 16) ^ ((row & 7) << 4);
                bf16x8 k0 = *(const bf16x8*)(Kc + row * 128 + kb0);
                bf16x8 k1 = *(const bf16x8*)(Kc + row * 128 + kb1);
                accs[kf] = __builtin_amdgcn_mfma_f32_16x16x32_bf16(k0, qf0, accs[kf], 0, 0, 0);
                accs[kf] = __builtin_amdgcn_mfma_f32_16x16x32_bf16(k1, qf1, accs[kf], 0, 0, 0);
            }
            float pm = -3.0e38f;
            #pragma unroll
            for (int kf = 0; kf < 4; kf++)
                #pragma unroll
                for (int r = 0; r < 4; r++) pm = fmaxf(pm, accs[kf][r]);
            pm = fmaxf(pm, __shfl_xor(pm, 16));
            pm = fmaxf(pm, __shfl_xor(pm, 32));
            float mnew = fmaxf(mrun, pm);
            float corr = __expf(mrun - mnew);
            mrun = mnew;
            float psum = 0.f;
            #pragma unroll
            for (int kf = 0; kf < 4; kf++)
                #pragma unroll
                for (int r = 0; r < 4; r++) {
                    float pv = __expf(accs[kf][r] - mnew);
                    accs[kf][r] = pv;
                    psum += pv;
                }
            psum += __shfl_xor(psum, 16);
            psum += __shfl_xor(psum, 32);
            lrun = lrun * corr + psum;
            #pragma unroll
            for (int kf = 0; kf < 4; kf++)
                #pragma unroll
                for (int rp = 0; rp < 4; rp += 2) {
                    unsigned pv = pk2(accs[kf][rp], accs[kf][rp + 1]);
                    int boff = (t * 128 + (16 * kf + 4 * g + rp) * 2) ^ ((t & 7) << 4);
                    *(unsigned*)(pw + boff) = pv;
                }
            float cr[4];
            #pragma unroll
            for (int r = 0; r < 4; r++) cr[r] = __shfl(corr, g * 4 + r);
            #pragma unroll
            for (int ni = 0; ni < 4; ni++)
                #pragma unroll
                for (int r = 0; r < 4; r++) acc_o[ni][r] *= cr[r];
            #pragma unroll
            for (int ks = 0; ks < 2; ks++) {
                bf16x8 pa = *(const bf16x8*)(pw + ((t * 128 + 64 * ks + 16 * g) ^ ((t & 7) << 4)));
                #pragma unroll
                for (int ni = 0; ni < 4; ni++) {
                    int row = ni * 16 + t;
                    int vb = (64 * ks + 16 * g) ^ ((row & 7) << 4);
                    bf16x8 vbf = *(const bf16x8*)(Vc + row * 128 + vb);
                    acc_o[ni] = __builtin_amdgcn_mfma_f32_16x16x32_bf16(pa, vbf, acc_o[ni], 0, 0, 0);
                }
            }
        }
        float inv = 1.0f / lrun;
        float ir[4];
        #pragma unroll
        for (int r = 0; r < 4; r++) ir[r] = __shfl(inv, g * 4 + r);
        #pragma unroll
        for (int ni = 0; ni < 4; ni++)
            #pragma unroll
            for (int r = 0; r < 4; r++) {
                int row = qbase + wv * 16 + g * 4 + r;
                int col = h * 64 + ni * 16 + t;
                obf[(size_t)row * DIM + col] = f2bf(acc_o[ni][r] * ir[r]);
            }
    }
}

// ---------------- driver ----------------------------------------------------------
extern "C" void kernel_launch(void* const* d_in, const int* in_sizes, int n_in,
                              void* d_out, int out_size, void* d_ws, size_t ws_size,
                              hipStream_t stream) {
    const float* tokens       = (const float*)d_in[0];
    const float* attn_norm_w  = (const float*)d_in[1];
    const float* w_qkv        = (const float*)d_in[2];
    const float* w_attn_out   = (const float*)d_in[3];
    const float* w_mix        = (const float*)d_in[4];
    const float* b_mix        = (const float*)d_in[5];
    const float* ff_norm_w    = (const float*)d_in[6];
    const float* w_ff_in      = (const float*)d_in[7];
    const float* b_ff_in      = (const float*)d_in[8];
    const float* w_ff_out     = (const float*)d_in[9];
    const float* b_ff_out     = (const float*)d_in[10];
    const float* final_norm_w = (const float*)d_in[11];

    char* p = (char*)d_ws;
    auto alloc = [&](size_t bytes) {
        char* r = p;
        p += (bytes + 255) & ~(size_t)255;
        return r;
    };
    short* wq_t  = (short*)alloc(4ull * 3072 * 1024 * 2);
    short* wo_t  = (short*)alloc(4ull * 1024 * 1024 * 2);
    short* wfa_t = (short*)alloc(4ull * FFNP * 1024 * 2);
    short* wfg_t = (short*)alloc(4ull * FFNP * 1024 * 2);
    short* wfo_t = (short*)alloc(4ull * 1024 * FFHP * 2);
    float* PART  = (float*)alloc(2ull * NTOK * 3072 * 4);  // union: qkv x2 | out x4
    float* X     = (float*)alloc((size_t)NTOK * DIM * 4);
    float* H     = (float*)alloc((size_t)NTOK * DIM * 4);
    float* FV    = (float*)alloc((size_t)NTOK * DIM * 4);
    float* MIX   = (float*)alloc((size_t)NTOK * HEADS * 4);
    short* Hbf   = (short*)alloc((size_t)NTOK * DIM * 2);
    short* Obf   = (short*)alloc((size_t)NTOK * DIM * 2);
    short* ACTbf = (short*)alloc((size_t)NTOK * FFHP * 2);
    unsigned short* Qbf = (unsigned short*)alloc((size_t)NTOK * DIM * 2);
    unsigned short* Kbf = (unsigned short*)alloc((size_t)NTOK * DIM * 2);
    unsigned short* Vtg = (unsigned short*)alloc((size_t)HEADS * 64 * NTOK * 2);
    float* PART1 = PART + (size_t)NTOK * 3072;

    // weight convert+transpose (bf16, [N][K] with zero padding)
    for (int i = 0; i < DEPTH; i++) {
        wconv_k<<<dim3(48, 16), 256, 0, stream>>>(
            w_qkv + (size_t)i * 1024 * 3072, wq_t + (size_t)i * 3072 * 1024,
            1024, 3072, 0, 3072, 1024, 3072);
        wconv_k<<<dim3(16, 16), 256, 0, stream>>>(
            w_attn_out + (size_t)i * 1024 * 1024, wo_t + (size_t)i * 1024 * 1024,
            1024, 1024, 0, 1024, 1024, 1024);
        wconv_k<<<dim3(44, 16), 256, 0, stream>>>(
            w_ff_in + (size_t)i * 1024 * FF2, wfa_t + (size_t)i * FFNP * 1024,
            1024, FFH, 0, FF2, 1024, FFNP);
        wconv_k<<<dim3(44, 16), 256, 0, stream>>>(
            w_ff_in + (size_t)i * 1024 * FF2, wfg_t + (size_t)i * FFNP * 1024,
            1024, FFH, FFH, FF2, 1024, FFNP);
        wconv_k<<<dim3(16, 43), 256, 0, stream>>>(
            w_ff_out + (size_t)i * FFH * 1024, wfo_t + (size_t)i * 1024 * FFHP,
            FFH, 1024, 0, 1024, FFHP, 1024);
    }

    hipMemcpyAsync(X, tokens, (size_t)NTOK * DIM * sizeof(float),
                   hipMemcpyDeviceToDevice, stream);
    // layer-0 attention norm (layers 1-3 get theirs fused into ff_out reduce)
    rmsnorm_k<<<NTOK, 256, 0, stream>>>(X, attn_norm_w, H, (unsigned short*)Hbf);

    for (int i = 0; i < DEPTH; i++) {
        gemm_splitk_k<2><<<dim3(24, 16, 2), 256, 0, stream>>>(
            Hbf, wq_t + (size_t)i * 3072 * 1024, PART, 3072, 1024);
        if (i > 0)
            mix_k<<<NTOK, 256, 0, stream>>>(H, w_mix + (size_t)i * DIM * HEADS,
                                            b_mix + (size_t)i * HEADS, MIX);
        rope_lerp_k<<<NTOK, 256, 0, stream>>>(PART, PART1, Qbf, Kbf);
        vtrans_k<<<dim3(16, 32), 256, 0, stream>>>(PART, PART1, FV, MIX, Vtg, i);
        attn_mfma_k<<<dim3(16, 16), 256, 0, stream>>>(Qbf, Kbf, Vtg,
                                                      (unsigned short*)Obf);
        gemm_splitk_k<4><<<dim3(8, 16, 4), 256, 0, stream>>>(
            Obf, wo_t + (size_t)i * 1024 * 1024, PART, 1024, 1024);
        rmsnorm_red_k<4><<<NTOK, 256, 0, stream>>>(
            X, PART, nullptr, ff_norm_w + (size_t)i * DIM, X, nullptr,
            (unsigned short*)Hbf);
        gemm_swiglu_k<<<dim3(43, 16), 256, 0, stream>>>(
            Hbf, wfa_t + (size_t)i * FFNP * 1024, wfg_t + (size_t)i * FFNP * 1024,
            b_ff_in + (size_t)i * FF2, (unsigned short*)ACTbf);
        gemm_splitk_k<4><<<dim3(8, 16, 4), 256, 0, stream>>>(
            ACTbf, wfo_t + (size_t)i * 1024 * FFHP, PART, 1024, FFHP);
        if (i < DEPTH - 1) {
            rmsnorm_red_k<4><<<NTOK, 256, 0, stream>>>(
                X, PART, b_ff_out + (size_t)i * DIM, attn_norm_w + (size_t)(i + 1) * DIM,
                X, H, (unsigned short*)Hbf);
        } else {
            rmsnorm_red_k<4><<<NTOK, 256, 0, stream>>>(
                X, PART, b_ff_out + (size_t)i * DIM, final_norm_w,
                nullptr, (float*)d_out, nullptr);
        }
    }
}

// Round 10
// 891.037 us; speedup vs baseline: 1.0840x; 1.0840x over previous
//
#include <hip/hip_runtime.h>
#include <hip/hip_bf16.h>

#define DIM   1024
#define NTOK  2048
#define HEADS 16
#define FFH   2730
#define FF2   5460
#define FFHP  2752   /* FFH padded to x64 */
#define FFNP  2816   /* FFH padded to x128 */
#define DEPTH 4
#define EPS_RMS 1.1920929e-07f
#define QK_SCALE 0.125f

typedef __attribute__((ext_vector_type(8))) short bf16x8;
typedef __attribute__((ext_vector_type(4))) float f32x4;

__device__ __forceinline__ unsigned short f2bf(float x) {
    unsigned u = __float_as_uint(x);
    u += 0x7fffu + ((u >> 16) & 1);          // RNE
    return (unsigned short)(u >> 16);
}
__device__ __forceinline__ float bf2f(unsigned short u) {
    return __uint_as_float((unsigned)u << 16);
}
__device__ __forceinline__ unsigned pk2(float a, float b) {
    unsigned ua = __float_as_uint(a); ua += 0x7fffu + ((ua >> 16) & 1);
    unsigned ub = __float_as_uint(b); ub += 0x7fffu + ((ub >> 16) & 1);
    return (ua >> 16) | (ub & 0xffff0000u);
}
// async global->LDS, 16B per lane; dest must be wave-uniform base + lane*16
__device__ __forceinline__ void gll16(const void* g, void* l) {
    __builtin_amdgcn_global_load_lds(
        (const __attribute__((address_space(1))) void*)g,
        (__attribute__((address_space(3))) void*)l, 16, 0, 0);
}

// ---------------- RMSNorm (layer-0 attn norm): fp32 out + bf16 out ---------------
__global__ void rmsnorm_k(const float* __restrict__ in, const float* __restrict__ w,
                          float* __restrict__ out, unsigned short* __restrict__ outbf) {
    int row = blockIdx.x;
    int tid = threadIdx.x;
    const float4* in4 = (const float4*)(in + (size_t)row * DIM);
    float4 v = in4[tid];
    float ss = v.x * v.x + v.y * v.y + v.z * v.z + v.w * v.w;
    #pragma unroll
    for (int off = 32; off > 0; off >>= 1) ss += __shfl_down(ss, off);
    __shared__ float lds[4];
    __shared__ float stot;
    int wid = tid >> 6, lane = tid & 63;
    if (lane == 0) lds[wid] = ss;
    __syncthreads();
    if (tid == 0) stot = lds[0] + lds[1] + lds[2] + lds[3];
    __syncthreads();
    float inv = 1.0f / sqrtf(stot * (1.0f / DIM) + EPS_RMS);
    const float4* w4 = (const float4*)w;
    float4 wv = w4[tid];
    float4 o;
    o.x = v.x * inv * wv.x; o.y = v.y * inv * wv.y;
    o.z = v.z * inv * wv.z; o.w = v.w * inv * wv.w;
    ((float4*)(out + (size_t)row * DIM))[tid] = o;
    if (outbf) {
        unsigned long long p = (unsigned long long)pk2(o.x, o.y)
                             | ((unsigned long long)pk2(o.z, o.w) << 32);
        ((unsigned long long*)(outbf + (size_t)row * DIM))[tid] = p;
    }
}

// ---------------- fused residual-reduce (bf16 partials) + RMSNorm ----------------
template<int S>
__global__ void rmsnorm_red_k(const float* __restrict__ X,
                              const unsigned short* __restrict__ P,
                              const float* __restrict__ bias, const float* __restrict__ w,
                              float* __restrict__ Xout, float* __restrict__ Hf,
                              unsigned short* __restrict__ Hbf) {
    int row = blockIdx.x;
    int tid = threadIdx.x;
    float4 x = ((const float4*)(X + (size_t)row * DIM))[tid];
    #pragma unroll
    for (int s = 0; s < S; s++) {
        ushort4 p = ((const ushort4*)(P + (size_t)s * NTOK * DIM + (size_t)row * DIM))[tid];
        x.x += bf2f(p.x); x.y += bf2f(p.y); x.z += bf2f(p.z); x.w += bf2f(p.w);
    }
    if (bias) {
        float4 b = ((const float4*)bias)[tid];
        x.x += b.x; x.y += b.y; x.z += b.z; x.w += b.w;
    }
    float ss = x.x * x.x + x.y * x.y + x.z * x.z + x.w * x.w;
    #pragma unroll
    for (int off = 32; off > 0; off >>= 1) ss += __shfl_down(ss, off);
    __shared__ float lds[4];
    __shared__ float stot;
    int wid = tid >> 6, lane = tid & 63;
    if (lane == 0) lds[wid] = ss;
    __syncthreads();
    if (tid == 0) stot = lds[0] + lds[1] + lds[2] + lds[3];
    __syncthreads();
    float inv = 1.0f / sqrtf(stot * (1.0f / DIM) + EPS_RMS);
    if (Xout) ((float4*)(Xout + (size_t)row * DIM))[tid] = x;
    float4 wv = ((const float4*)w)[tid];
    float4 o;
    o.x = x.x * inv * wv.x; o.y = x.y * inv * wv.y;
    o.z = x.z * inv * wv.z; o.w = x.w * inv * wv.w;
    if (Hf) ((float4*)(Hf + (size_t)row * DIM))[tid] = o;
    if (Hbf) {
        unsigned long long p = (unsigned long long)pk2(o.x, o.y)
                             | ((unsigned long long)pk2(o.z, o.w) << 32);
        ((unsigned long long*)(Hbf + (size_t)row * DIM))[tid] = p;
    }
}

// ---------------- weight transpose+convert: W fp32 [Ksrc][stride] -> bf16 [Np][Kp]
__global__ __launch_bounds__(256) void wconv_k(
        const float* __restrict__ W, short* __restrict__ out,
        int Ksrc, int Nsrc, int colOfs, int rowStride, int Kp, int Np) {
    __shared__ float tile[64][65];
    int k0 = blockIdx.y * 64, n0 = blockIdx.x * 64;
    int tid = threadIdx.x;
    int c = tid & 63;
    #pragma unroll
    for (int kk4 = 0; kk4 < 16; kk4++) {
        int kk = kk4 * 4 + (tid >> 6);
        int gk = k0 + kk, gn = n0 + c;
        float v = 0.f;
        if (gk < Ksrc && gn < Nsrc) v = W[(size_t)gk * rowStride + colOfs + gn];
        tile[kk][c] = v;
    }
    __syncthreads();
    #pragma unroll
    for (int it = 0; it < 4; it++) {
        int flat = tid + 256 * it;
        int nn = flat >> 4, kg = (flat & 15) * 4;
        int gn = n0 + nn, gk = k0 + kg;
        if (gn < Np && gk < Kp) {
            short4 s;
            s.x = (short)f2bf(tile[kg + 0][nn]);
            s.y = (short)f2bf(tile[kg + 1][nn]);
            s.z = (short)f2bf(tile[kg + 2][nn]);
            s.w = (short)f2bf(tile[kg + 3][nn]);
            *(short4*)(out + (size_t)gn * Kp + gk) = s;
        }
    }
}

// ---------------- bf16 MFMA GEMM, split-K (round-8 single-buffered body) ---------
// 128x128 tile, BK=64, 4 waves (2x2). Staging via global_load_lds width=16:
// linear LDS dest, XOR swizzle folded into the GLOBAL source column. Block z
// writes its partial slice; OUT16 selects bf16 (out-GEMMs) vs fp32 (qkv direct).
template<int SPLITK, int OUT16>
__global__ __launch_bounds__(256, 2) void gemm_splitk_k(
        const short* __restrict__ A, const short* __restrict__ Bt,
        void* __restrict__ Cpart, int N, int Kp) {
    __shared__ __align__(16) short As[128 * 64];
    __shared__ __align__(16) short Bs[128 * 64];
    int tid = threadIdx.x;
    int wv = tid >> 6, ln = tid & 63, g = ln >> 4, t = ln & 15;
    int wr = wv >> 1, wc = wv & 1;
    int rowBase = blockIdx.y * 128, colBase = blockIdx.x * 128;
    f32x4 acc[4][4] = {};
    int KT = Kp >> 6;
    int kt0 = (KT * blockIdx.z) / SPLITK, kt1 = (KT * (blockIdx.z + 1)) / SPLITK;
    for (int kt = kt0; kt < kt1; kt++) {
        int k0 = kt * 64;
        #pragma unroll
        for (int i = 0; i < 4; i++) {
            int idx = tid + 256 * i;
            int r = idx >> 3, c8 = idx & 7;
            int cs = (c8 ^ (r & 7)) * 8;
            gll16(A + (size_t)(rowBase + r) * Kp + k0 + cs, (char*)As + idx * 16);
            gll16(Bt + (size_t)(colBase + r) * Kp + k0 + cs, (char*)Bs + idx * 16);
        }
        __syncthreads();
        #pragma unroll
        for (int ks = 0; ks < 2; ks++) {
            bf16x8 af[4], bf[4];
            #pragma unroll
            for (int mi = 0; mi < 4; mi++) {
                int row = wr * 64 + mi * 16 + t;
                int kb = (ks * 64 + g * 16) ^ ((row & 7) << 4);
                af[mi] = *(const bf16x8*)((const char*)As + row * 128 + kb);
            }
            #pragma unroll
            for (int ni = 0; ni < 4; ni++) {
                int row = wc * 64 + ni * 16 + t;
                int kb = (ks * 64 + g * 16) ^ ((row & 7) << 4);
                bf[ni] = *(const bf16x8*)((const char*)Bs + row * 128 + kb);
            }
            #pragma unroll
            for (int mi = 0; mi < 4; mi++)
                #pragma unroll
                for (int ni = 0; ni < 4; ni++)
                    acc[mi][ni] = __builtin_amdgcn_mfma_f32_16x16x32_bf16(
                        af[mi], bf[ni], acc[mi][ni], 0, 0, 0);
        }
        __syncthreads();
    }
    #pragma unroll
    for (int mi = 0; mi < 4; mi++)
        #pragma unroll
        for (int ni = 0; ni < 4; ni++) {
            int col = colBase + wc * 64 + ni * 16 + t;
            #pragma unroll
            for (int r = 0; r < 4; r++) {
                int row = rowBase + wr * 64 + mi * 16 + g * 4 + r;
                if (OUT16) {
                    unsigned short* Cz = (unsigned short*)Cpart
                                       + (size_t)blockIdx.z * NTOK * N;
                    Cz[(size_t)row * N + col] = f2bf(acc[mi][ni][r]);
                } else {
                    float* Cz = (float*)Cpart + (size_t)blockIdx.z * NTOK * N;
                    Cz[(size_t)row * N + col] = acc[mi][ni][r];
                }
            }
        }
}

// ---------------- SwiGLU fused GEMM (round-8 body): 128x128, gll16 staging -------
__global__ __launch_bounds__(256, 2) void gemm_swiglu_k(
        const short* __restrict__ A, const short* __restrict__ Ba,
        const short* __restrict__ Bg, const float* __restrict__ biasIn,
        unsigned short* __restrict__ actbf) {
    __shared__ __align__(16) short As[128 * 64];
    __shared__ __align__(16) short B1[128 * 64];
    __shared__ __align__(16) short B2[128 * 64];
    int tid = threadIdx.x;
    int wv = tid >> 6, ln = tid & 63, g = ln >> 4, t = ln & 15;
    int wr = wv >> 1, wc = wv & 1;
    int rowBase = blockIdx.y * 128, colBase = blockIdx.x * 128;
    f32x4 acca[4][4] = {};
    f32x4 accg[4][4] = {};
    for (int kt = 0; kt < 16; kt++) {
        int k0 = kt * 64;
        #pragma unroll
        for (int i = 0; i < 4; i++) {
            int idx = tid + 256 * i;
            int r = idx >> 3, c8 = idx & 7;
            int cs = (c8 ^ (r & 7)) * 8;
            gll16(A + (size_t)(rowBase + r) * 1024 + k0 + cs, (char*)As + idx * 16);
            gll16(Ba + (size_t)(colBase + r) * 1024 + k0 + cs, (char*)B1 + idx * 16);
            gll16(Bg + (size_t)(colBase + r) * 1024 + k0 + cs, (char*)B2 + idx * 16);
        }
        __syncthreads();
        #pragma unroll
        for (int ks = 0; ks < 2; ks++) {
            bf16x8 af[4], b1f[4], b2f[4];
            #pragma unroll
            for (int mi = 0; mi < 4; mi++) {
                int row = wr * 64 + mi * 16 + t;
                int kb = (ks * 64 + g * 16) ^ ((row & 7) << 4);
                af[mi] = *(const bf16x8*)((const char*)As + row * 128 + kb);
            }
            #pragma unroll
            for (int ni = 0; ni < 4; ni++) {
                int row = wc * 64 + ni * 16 + t;
                int kb = (ks * 64 + g * 16) ^ ((row & 7) << 4);
                b1f[ni] = *(const bf16x8*)((const char*)B1 + row * 128 + kb);
                b2f[ni] = *(const bf16x8*)((const char*)B2 + row * 128 + kb);
            }
            #pragma unroll
            for (int mi = 0; mi < 4; mi++)
                #pragma unroll
                for (int ni = 0; ni < 4; ni++) {
                    acca[mi][ni] = __builtin_amdgcn_mfma_f32_16x16x32_bf16(
                        af[mi], b1f[ni], acca[mi][ni], 0, 0, 0);
                    accg[mi][ni] = __builtin_amdgcn_mfma_f32_16x16x32_bf16(
                        af[mi], b2f[ni], accg[mi][ni], 0, 0, 0);
                }
        }
        __syncthreads();
    }
    const float rs2 = 0.70710678118654752f;
    #pragma unroll
    for (int mi = 0; mi < 4; mi++)
        #pragma unroll
        for (int ni = 0; ni < 4; ni++) {
            int col = colBase + wc * 64 + ni * 16 + t;
            if (col < FFHP) {
                float ba = (col < FFH) ? biasIn[col] : 0.f;
                float bg = (col < FFH) ? biasIn[FFH + col] : 0.f;
                #pragma unroll
                for (int r = 0; r < 4; r++) {
                    int row = rowBase + wr * 64 + mi * 16 + g * 4 + r;
                    unsigned short outv = 0;
                    if (col < FFH) {
                        float a_ = acca[mi][ni][r] + ba;
                        float g_ = accg[mi][ni][r] + bg;
                        float gel = 0.5f * g_ * (1.0f + erff(g_ * rs2));
                        outv = f2bf(a_ * gel);
                    }
                    actbf[(size_t)row * FFHP + col] = outv;
                }
            }
        }
}

// ---------------- mix = sigmoid(h @ w_mix + b_mix) -------------------------------
__global__ void mix_k(const float* __restrict__ h, const float* __restrict__ wm,
                      const float* __restrict__ bm, float* __restrict__ mix) {
    int row = blockIdx.x;
    int tid = threadIdx.x;
    int hh = tid & 15, kl = tid >> 4;
    const float* hr = h + (size_t)row * DIM;
    float p = 0.f;
    for (int j = 0; j < 64; j++) {
        int k = kl + 16 * j;
        p += hr[k] * wm[k * 16 + hh];
    }
    __shared__ float lds[256];
    lds[tid] = p;
    __syncthreads();
    if (tid < 16) {
        float s = 0.f;
        #pragma unroll
        for (int k2 = 0; k2 < 16; k2++) s += lds[k2 * 16 + tid];
        s += bm[tid];
        mix[row * HEADS + tid] = 1.0f / (1.0f + expf(-s));
    }
}

// ---------------- RoPE on q,k -> bf16 (q pre-scaled) -----------------------------
__global__ void rope_lerp_k(const float* __restrict__ qkv,
                            unsigned short* __restrict__ qbf,
                            unsigned short* __restrict__ kbf) {
    int row = blockIdx.x;
    int tid = threadIdx.x;
    const float* qr = qkv + (size_t)row * 3072;
    #pragma unroll
    for (int it = 0; it < 2; it++) {
        int p = tid + 256 * it;
        int hh = p >> 5, pr = p & 31;
        float freq = expf(-(float)pr * (1.0f / 32.0f) * 9.2103403719762f);
        float ang = (float)row * freq;
        float s, c;
        sincosf(ang, &s, &c);
        int base = hh * 64 + pr * 2;
        float q0 = qr[base], q1 = qr[base + 1];
        float qa = q0 * c - q1 * s, qb = q1 * c + q0 * s;
        *(unsigned*)(qbf + (size_t)row * DIM + base) = pk2(qa * QK_SCALE, qb * QK_SCALE);
        float k0 = qr[1024 + base], k1 = qr[1024 + base + 1];
        *(unsigned*)(kbf + (size_t)row * DIM + base) = pk2(k0 * c - k1 * s, k1 * c + k0 * s);
    }
}

// ---------------- V: value-residual lerp + transpose -> Vtg[h][d][n] bf16 --------
__global__ __launch_bounds__(256) void vtrans_k(
        const float* __restrict__ qkv, float* __restrict__ fv,
        const float* __restrict__ mix, unsigned short* __restrict__ vtg, int layer) {
    __shared__ __align__(16) short T[64 * 64];
    int h = blockIdx.x, n0 = blockIdx.y * 64;
    int tid = threadIdx.x;
    #pragma unroll
    for (int it = 0; it < 2; it++) {
        int flat = tid + 256 * it;
        int n = flat >> 3, d0 = (flat & 7) * 8;
        int row = n0 + n;
        const float* src = qkv + (size_t)row * 3072 + 2048 + h * 64 + d0;
        float4 u0 = *(const float4*)src;
        float4 u1 = *(const float4*)(src + 4);
        float vals[8] = {u0.x, u0.y, u0.z, u0.w, u1.x, u1.y, u1.z, u1.w};
        float* fvp = fv + (size_t)row * DIM + h * 64 + d0;
        if (layer == 0) {
            *(float4*)fvp = u0;
            *(float4*)(fvp + 4) = u1;
        } else {
            float m = mix[row * HEADS + h];
            float4 f0 = *(const float4*)fvp;
            float4 f1 = *(const float4*)(fvp + 4);
            float fvv[8] = {f0.x, f0.y, f0.z, f0.w, f1.x, f1.y, f1.z, f1.w};
            #pragma unroll
            for (int e = 0; e < 8; e++) vals[e] += m * (fvv[e] - vals[e]);
        }
        #pragma unroll
        for (int e = 0; e < 8; e++) {
            int d = d0 + e;
            *(short*)((char*)T + d * 128 + ((2 * n) ^ ((d & 7) << 4))) = (short)f2bf(vals[e]);
        }
    }
    __syncthreads();
    #pragma unroll
    for (int it = 0; it < 2; it++) {
        int flat = tid + 256 * it;
        int d = flat >> 3, nn0 = (flat & 7) * 8;
        uint4 v = *(const uint4*)((const char*)T + d * 128 + ((2 * nn0) ^ ((d & 7) << 4)));
        *(uint4*)(vtg + (size_t)(h * 64 + d) * NTOK + n0 + nn0) = v;
    }
}

// ---------------- MFMA flash attention: balanced paired q-tiles ------------------
__global__ __launch_bounds__(256, 2) void attn_mfma_k(
        const unsigned short* __restrict__ Qbf, const unsigned short* __restrict__ Kbf,
        const unsigned short* __restrict__ Vtg, unsigned short* __restrict__ obf) {
    const int h = blockIdx.x, pri = blockIdx.y;
    const int tid = threadIdx.x;
    const int wv = tid >> 6, ln = tid & 63, g = ln >> 4, t = ln & 15;
    __shared__ __align__(16) short KsB[2][64 * 64];
    __shared__ __align__(16) short VtB[2][64 * 64];
    __shared__ __align__(16) short Plds[4 * 16 * 64];
    char* pw = (char*)(Plds + wv * 1024);

    const int sr = ln >> 3;
    const int scol = (ln & 7) ^ sr;                 // swizzle on global source
    const int sbyte0 = (wv * 16 + sr) * 128 + (ln & 7) * 16;
    const int sbyte1 = sbyte0 + 8 * 128;
    const unsigned short* kgl0 = Kbf + (size_t)(wv * 16 + sr) * DIM + h * 64 + scol * 8;
    const unsigned short* kgl1 = kgl0 + 8 * DIM;
    const unsigned short* vgl0 = Vtg + (size_t)(h * 64 + wv * 16 + sr) * NTOK + scol * 8;
    const unsigned short* vgl1 = vgl0 + 8 * NTOK;

    for (int ph = 0; ph < 2; ph++) {
        const int j = ph ? (31 - pri) : pri;
        const int nch = ((j >> 1) + 1) * 2;
        const int qbase = j * 64;
        const unsigned short* qrow = Qbf + (size_t)(qbase + wv * 16 + t) * DIM + h * 64;
        bf16x8 qf0 = *(const bf16x8*)(qrow + 8 * g);
        bf16x8 qf1 = *(const bf16x8*)(qrow + 32 + 8 * g);
        f32x4 acc_o[4] = {};
        float mrun = -3.0e38f, lrun = 0.f;
        uint4 rk0 = *(const uint4*)kgl0;
        uint4 rk1 = *(const uint4*)kgl1;
        uint4 rv0 = *(const uint4*)vgl0;
        uint4 rv1 = *(const uint4*)vgl1;
        for (int kc = 0; kc < nch; kc++) {
            const int cur = kc & 1;
            *(uint4*)((char*)KsB[cur] + sbyte0) = rk0;
            *(uint4*)((char*)KsB[cur] + sbyte1) = rk1;
            *(uint4*)((char*)VtB[cur] + sbyte0) = rv0;
            *(uint4*)((char*)VtB[cur] + sbyte1) = rv1;
            if (kc + 1 < nch) {
                rk0 = *(const uint4*)(kgl0 + (size_t)(kc + 1) * 64 * DIM);
                rk1 = *(const uint4*)(kgl1 + (size_t)(kc + 1) * 64 * DIM);
                rv0 = *(const uint4*)(vgl0 + (kc + 1) * 64);
                rv1 = *(const uint4*)(vgl1 + (kc + 1) * 64);
            }
            __syncthreads();
            const char* Kc = (const char*)KsB[cur];
            const char* Vc = (const char*)VtB[cur];
            f32x4 accs[4] = {};
            #pragma unroll
            for (int kf = 0; kf < 4; kf++) {
                int row = kf * 16 + t;
                int kb0 = (g * 16) ^ ((row & 7) << 4);
                int kb1 = (64 + g * 16) ^ ((row & 7) << 4);
                bf16x8 k0 = *(const bf16x8*)(Kc + row * 128 + kb0);
                bf16x8 k1 = *(const bf16x8*)(Kc + row * 128 + kb1);
                accs[kf] = __builtin_amdgcn_mfma_f32_16x16x32_bf16(k0, qf0, accs[kf], 0, 0, 0);
                accs[kf] = __builtin_amdgcn_mfma_f32_16x16x32_bf16(k1, qf1, accs[kf], 0, 0, 0);
            }
            float pm = -3.0e38f;
            #pragma unroll
            for (int kf = 0; kf < 4; kf++)
                #pragma unroll
                for (int r = 0; r < 4; r++) pm = fmaxf(pm, accs[kf][r]);
            pm = fmaxf(pm, __shfl_xor(pm, 16));
            pm = fmaxf(pm, __shfl_xor(pm, 32));
            float mnew = fmaxf(mrun, pm);
            float corr = __expf(mrun - mnew);
            mrun = mnew;
            float psum = 0.f;
            #pragma unroll
            for (int kf = 0; kf < 4; kf++)
                #pragma unroll
                for (int r = 0; r < 4; r++) {
                    float pv = __expf(accs[kf][r] - mnew);
                    accs[kf][r] = pv;
                    psum += pv;
                }
            psum += __shfl_xor(psum, 16);
            psum += __shfl_xor(psum, 32);
            lrun = lrun * corr + psum;
            #pragma unroll
            for (int kf = 0; kf < 4; kf++)
                #pragma unroll
                for (int rp = 0; rp < 4; rp += 2) {
                    unsigned pv = pk2(accs[kf][rp], accs[kf][rp + 1]);
                    int boff = (t * 128 + (16 * kf + 4 * g + rp) * 2) ^ ((t & 7) << 4);
                    *(unsigned*)(pw + boff) = pv;
                }
            float cr[4];
            #pragma unroll
            for (int r = 0; r < 4; r++) cr[r] = __shfl(corr, g * 4 + r);
            #pragma unroll
            for (int ni = 0; ni < 4; ni++)
                #pragma unroll
                for (int r = 0; r < 4; r++) acc_o[ni][r] *= cr[r];
            #pragma unroll
            for (int ks = 0; ks < 2; ks++) {
                bf16x8 pa = *(const bf16x8*)(pw + ((t * 128 + 64 * ks + 16 * g) ^ ((t & 7) << 4)));
                #pragma unroll
                for (int ni = 0; ni < 4; ni++) {
                    int row = ni * 16 + t;
                    int vb = (64 * ks + 16 * g) ^ ((row & 7) << 4);
                    bf16x8 vbf = *(const bf16x8*)(Vc + row * 128 + vb);
                    acc_o[ni] = __builtin_amdgcn_mfma_f32_16x16x32_bf16(pa, vbf, acc_o[ni], 0, 0, 0);
                }
            }
        }
        float inv = 1.0f / lrun;
        float ir[4];
        #pragma unroll
        for (int r = 0; r < 4; r++) ir[r] = __shfl(inv, g * 4 + r);
        #pragma unroll
        for (int ni = 0; ni < 4; ni++)
            #pragma unroll
            for (int r = 0; r < 4; r++) {
                int row = qbase + wv * 16 + g * 4 + r;
                int col = h * 64 + ni * 16 + t;
                obf[(size_t)row * DIM + col] = f2bf(acc_o[ni][r] * ir[r]);
            }
    }
}

// ---------------- driver ----------------------------------------------------------
extern "C" void kernel_launch(void* const* d_in, const int* in_sizes, int n_in,
                              void* d_out, int out_size, void* d_ws, size_t ws_size,
                              hipStream_t stream) {
    const float* tokens       = (const float*)d_in[0];
    const float* attn_norm_w  = (const float*)d_in[1];
    const float* w_qkv        = (const float*)d_in[2];
    const float* w_attn_out   = (const float*)d_in[3];
    const float* w_mix        = (const float*)d_in[4];
    const float* b_mix        = (const float*)d_in[5];
    const float* ff_norm_w    = (const float*)d_in[6];
    const float* w_ff_in      = (const float*)d_in[7];
    const float* b_ff_in      = (const float*)d_in[8];
    const float* w_ff_out     = (const float*)d_in[9];
    const float* b_ff_out     = (const float*)d_in[10];
    const float* final_norm_w = (const float*)d_in[11];

    char* p = (char*)d_ws;
    auto alloc = [&](size_t bytes) {
        char* r = p;
        p += (bytes + 255) & ~(size_t)255;
        return r;
    };
    short* wq_t  = (short*)alloc(4ull * 3072 * 1024 * 2);
    short* wo_t  = (short*)alloc(4ull * 1024 * 1024 * 2);
    short* wfa_t = (short*)alloc(4ull * FFNP * 1024 * 2);
    short* wfg_t = (short*)alloc(4ull * FFNP * 1024 * 2);
    short* wfo_t = (short*)alloc(4ull * 1024 * FFHP * 2);
    float* PART  = (float*)alloc((size_t)NTOK * 3072 * 4);  // union: qkv fp32 | out bf16 x4
    float* X     = (float*)alloc((size_t)NTOK * DIM * 4);
    float* H     = (float*)alloc((size_t)NTOK * DIM * 4);
    float* FV    = (float*)alloc((size_t)NTOK * DIM * 4);
    float* MIX   = (float*)alloc((size_t)NTOK * HEADS * 4);
    short* Hbf   = (short*)alloc((size_t)NTOK * DIM * 2);
    short* Obf   = (short*)alloc((size_t)NTOK * DIM * 2);
    short* ACTbf = (short*)alloc((size_t)NTOK * FFHP * 2);
    unsigned short* Qbf = (unsigned short*)alloc((size_t)NTOK * DIM * 2);
    unsigned short* Kbf = (unsigned short*)alloc((size_t)NTOK * DIM * 2);
    unsigned short* Vtg = (unsigned short*)alloc((size_t)HEADS * 64 * NTOK * 2);
    float* QKVf = PART;                                   // [NTOK][3072] fp32
    unsigned short* PARTb = (unsigned short*)PART;        // [4][NTOK][1024] bf16

    // weight convert+transpose (bf16, [N][K] with zero padding)
    for (int i = 0; i < DEPTH; i++) {
        wconv_k<<<dim3(48, 16), 256, 0, stream>>>(
            w_qkv + (size_t)i * 1024 * 3072, wq_t + (size_t)i * 3072 * 1024,
            1024, 3072, 0, 3072, 1024, 3072);
        wconv_k<<<dim3(16, 16), 256, 0, stream>>>(
            w_attn_out + (size_t)i * 1024 * 1024, wo_t + (size_t)i * 1024 * 1024,
            1024, 1024, 0, 1024, 1024, 1024);
        wconv_k<<<dim3(44, 16), 256, 0, stream>>>(
            w_ff_in + (size_t)i * 1024 * FF2, wfa_t + (size_t)i * FFNP * 1024,
            1024, FFH, 0, FF2, 1024, FFNP);
        wconv_k<<<dim3(44, 16), 256, 0, stream>>>(
            w_ff_in + (size_t)i * 1024 * FF2, wfg_t + (size_t)i * FFNP * 1024,
            1024, FFH, FFH, FF2, 1024, FFNP);
        wconv_k<<<dim3(16, 43), 256, 0, stream>>>(
            w_ff_out + (size_t)i * FFH * 1024, wfo_t + (size_t)i * 1024 * FFHP,
            FFH, 1024, 0, 1024, FFHP, 1024);
    }

    hipMemcpyAsync(X, tokens, (size_t)NTOK * DIM * sizeof(float),
                   hipMemcpyDeviceToDevice, stream);
    // layer-0 attention norm (layers 1-3 get theirs fused into ff_out reduce)
    rmsnorm_k<<<NTOK, 256, 0, stream>>>(X, attn_norm_w, H, (unsigned short*)Hbf);

    for (int i = 0; i < DEPTH; i++) {
        gemm_splitk_k<1, 0><<<dim3(24, 16, 1), 256, 0, stream>>>(
            Hbf, wq_t + (size_t)i * 3072 * 1024, QKVf, 3072, 1024);
        if (i > 0)
            mix_k<<<NTOK, 256, 0, stream>>>(H, w_mix + (size_t)i * DIM * HEADS,
                                            b_mix + (size_t)i * HEADS, MIX);
        rope_lerp_k<<<NTOK, 256, 0, stream>>>(QKVf, Qbf, Kbf);
        vtrans_k<<<dim3(16, 32), 256, 0, stream>>>(QKVf, FV, MIX, Vtg, i);
        attn_mfma_k<<<dim3(16, 16), 256, 0, stream>>>(Qbf, Kbf, Vtg,
                                                      (unsigned short*)Obf);
        gemm_splitk_k<4, 1><<<dim3(8, 16, 4), 256, 0, stream>>>(
            Obf, wo_t + (size_t)i * 1024 * 1024, PARTb, 1024, 1024);
        rmsnorm_red_k<4><<<NTOK, 256, 0, stream>>>(
            X, PARTb, nullptr, ff_norm_w + (size_t)i * DIM, X, nullptr,
            (unsigned short*)Hbf);
        gemm_swiglu_k<<<dim3(22, 16), 256, 0, stream>>>(
            Hbf, wfa_t + (size_t)i * FFNP * 1024, wfg_t + (size_t)i * FFNP * 1024,
            b_ff_in + (size_t)i * FF2, (unsigned short*)ACTbf);
        gemm_splitk_k<4, 1><<<dim3(8, 16, 4), 256, 0, stream>>>(
            ACTbf, wfo_t + (size_t)i * 1024 * FFHP, PARTb, 1024, FFHP);
        if (i < DEPTH - 1) {
            rmsnorm_red_k<4><<<NTOK, 256, 0, stream>>>(
                X, PARTb, b_ff_out + (size_t)i * DIM, attn_norm_w + (size_t)(i + 1) * DIM,
                X, H, (unsigned short*)Hbf);
        } else {
            rmsnorm_red_k<4><<<NTOK, 256, 0, stream>>>(
                X, PARTb, b_ff_out + (size_t)i * DIM, final_norm_w,
                nullptr, (float*)d_out, nullptr);
        }
    }
}

// Round 11
// 757.002 us; speedup vs baseline: 1.2759x; 1.1771x over previous
//
#include <hip/hip_runtime.h>
#include <hip/hip_bf16.h>

#define DIM   1024
#define NTOK  2048
#define HEADS 16
#define FFH   2730
#define FF2   5460
#define FFHP  2752   /* FFH padded to x64 */
#define FFNP  2816   /* FFH padded to x128 */
#define DEPTH 4
#define EPS_RMS 1.1920929e-07f
#define QK_SCALE 0.125f

typedef __attribute__((ext_vector_type(8))) short bf16x8;
typedef __attribute__((ext_vector_type(4))) float f32x4;

__device__ __forceinline__ unsigned short f2bf(float x) {
    unsigned u = __float_as_uint(x);
    u += 0x7fffu + ((u >> 16) & 1);          // RNE
    return (unsigned short)(u >> 16);
}
__device__ __forceinline__ float bf2f(unsigned short u) {
    return __uint_as_float((unsigned)u << 16);
}
__device__ __forceinline__ unsigned pk2(float a, float b) {
    unsigned ua = __float_as_uint(a); ua += 0x7fffu + ((ua >> 16) & 1);
    unsigned ub = __float_as_uint(b); ub += 0x7fffu + ((ub >> 16) & 1);
    return (ua >> 16) | (ub & 0xffff0000u);
}
// async global->LDS, 16B per lane; dest must be wave-uniform base + lane*16
__device__ __forceinline__ void gll16(const void* g, void* l) {
    __builtin_amdgcn_global_load_lds(
        (const __attribute__((address_space(1))) void*)g,
        (__attribute__((address_space(3))) void*)l, 16, 0, 0);
}

// ---------------- RMSNorm (layer-0 attn norm): bf16 out --------------------------
__global__ void rmsnorm_k(const float* __restrict__ in, const float* __restrict__ w,
                          unsigned short* __restrict__ outbf) {
    int row = blockIdx.x;
    int tid = threadIdx.x;
    const float4* in4 = (const float4*)(in + (size_t)row * DIM);
    float4 v = in4[tid];
    float ss = v.x * v.x + v.y * v.y + v.z * v.z + v.w * v.w;
    #pragma unroll
    for (int off = 32; off > 0; off >>= 1) ss += __shfl_down(ss, off);
    __shared__ float lds[4];
    __shared__ float stot;
    int wid = tid >> 6, lane = tid & 63;
    if (lane == 0) lds[wid] = ss;
    __syncthreads();
    if (tid == 0) stot = lds[0] + lds[1] + lds[2] + lds[3];
    __syncthreads();
    float inv = 1.0f / sqrtf(stot * (1.0f / DIM) + EPS_RMS);
    const float4* w4 = (const float4*)w;
    float4 wv = w4[tid];
    float4 o;
    o.x = v.x * inv * wv.x; o.y = v.y * inv * wv.y;
    o.z = v.z * inv * wv.z; o.w = v.w * inv * wv.w;
    unsigned long long p = (unsigned long long)pk2(o.x, o.y)
                         | ((unsigned long long)pk2(o.z, o.w) << 32);
    ((unsigned long long*)(outbf + (size_t)row * DIM))[tid] = p;
}

// ---------------- fused residual-reduce (bf16 partials) + RMSNorm [+ mix] --------
// x = X + sum_s P[s] (+bias); Xout=x; o = rmsnorm(x)*w -> Hf/Hbf;
// DOMIX: mix[row][h] = sigmoid(o . wm[:,h] + bm[h])  (replaces mix_k; exact order)
template<int S, int DOMIX>
__global__ void rmsnorm_red_k(const float* __restrict__ X,
                              const unsigned short* __restrict__ P,
                              const float* __restrict__ bias, const float* __restrict__ w,
                              float* __restrict__ Xout, float* __restrict__ Hf,
                              unsigned short* __restrict__ Hbf,
                              const float* __restrict__ wm, const float* __restrict__ bm,
                              float* __restrict__ mix) {
    int row = blockIdx.x;
    int tid = threadIdx.x;
    float4 x = ((const float4*)(X + (size_t)row * DIM))[tid];
    #pragma unroll
    for (int s = 0; s < S; s++) {
        ushort4 p = ((const ushort4*)(P + (size_t)s * NTOK * DIM + (size_t)row * DIM))[tid];
        x.x += bf2f(p.x); x.y += bf2f(p.y); x.z += bf2f(p.z); x.w += bf2f(p.w);
    }
    if (bias) {
        float4 b = ((const float4*)bias)[tid];
        x.x += b.x; x.y += b.y; x.z += b.z; x.w += b.w;
    }
    float ss = x.x * x.x + x.y * x.y + x.z * x.z + x.w * x.w;
    #pragma unroll
    for (int off = 32; off > 0; off >>= 1) ss += __shfl_down(ss, off);
    __shared__ float lds[4];
    __shared__ float stot;
    int wid = tid >> 6, lane = tid & 63;
    if (lane == 0) lds[wid] = ss;
    __syncthreads();
    if (tid == 0) stot = lds[0] + lds[1] + lds[2] + lds[3];
    __syncthreads();
    float inv = 1.0f / sqrtf(stot * (1.0f / DIM) + EPS_RMS);
    if (Xout) ((float4*)(Xout + (size_t)row * DIM))[tid] = x;
    float4 wv = ((const float4*)w)[tid];
    float4 o;
    o.x = x.x * inv * wv.x; o.y = x.y * inv * wv.y;
    o.z = x.z * inv * wv.z; o.w = x.w * inv * wv.w;
    if (Hf) ((float4*)(Hf + (size_t)row * DIM))[tid] = o;
    if (Hbf) {
        unsigned long long p = (unsigned long long)pk2(o.x, o.y)
                             | ((unsigned long long)pk2(o.z, o.w) << 32);
        ((unsigned long long*)(Hbf + (size_t)row * DIM))[tid] = p;
    }
    if (DOMIX) {
        __shared__ float olds[1024];
        __shared__ float red[256];
        ((float4*)olds)[tid] = o;
        __syncthreads();
        int hh = tid & 15, kl = tid >> 4;
        float pm = 0.f;
        #pragma unroll
        for (int j = 0; j < 64; j++) {
            int k = kl + 16 * j;
            pm += olds[k] * wm[k * 16 + hh];
        }
        red[tid] = pm;
        __syncthreads();
        if (tid < 16) {
            float s = 0.f;
            #pragma unroll
            for (int k2 = 0; k2 < 16; k2++) s += red[k2 * 16 + tid];
            s += bm[tid];
            mix[row * HEADS + tid] = 1.0f / (1.0f + expf(-s));
        }
    }
}

// ---------------- weight transpose+convert (batched over layers via z) -----------
__global__ __launch_bounds__(256) void wconv_k(
        const float* __restrict__ W0, short* __restrict__ out0,
        int Ksrc, int Nsrc, int colOfs, int rowStride, int Kp, int Np,
        size_t wStride, size_t oStride) {
    const float* W = W0 + (size_t)blockIdx.z * wStride;
    short* out = out0 + (size_t)blockIdx.z * oStride;
    __shared__ float tile[64][65];
    int k0 = blockIdx.y * 64, n0 = blockIdx.x * 64;
    int tid = threadIdx.x;
    int c = tid & 63;
    #pragma unroll
    for (int kk4 = 0; kk4 < 16; kk4++) {
        int kk = kk4 * 4 + (tid >> 6);
        int gk = k0 + kk, gn = n0 + c;
        float v = 0.f;
        if (gk < Ksrc && gn < Nsrc) v = W[(size_t)gk * rowStride + colOfs + gn];
        tile[kk][c] = v;
    }
    __syncthreads();
    #pragma unroll
    for (int it = 0; it < 4; it++) {
        int flat = tid + 256 * it;
        int nn = flat >> 4, kg = (flat & 15) * 4;
        int gn = n0 + nn, gk = k0 + kg;
        if (gn < Np && gk < Kp) {
            short4 s;
            s.x = (short)f2bf(tile[kg + 0][nn]);
            s.y = (short)f2bf(tile[kg + 1][nn]);
            s.z = (short)f2bf(tile[kg + 2][nn]);
            s.w = (short)f2bf(tile[kg + 3][nn]);
            *(short4*)(out + (size_t)gn * Kp + gk) = s;
        }
    }
}

// ---------------- bf16 MFMA GEMM, split-K (single-buffered, gll16 staging) -------
template<int SPLITK, int OUT16>
__global__ __launch_bounds__(256, 2) void gemm_splitk_k(
        const short* __restrict__ A, const short* __restrict__ Bt,
        void* __restrict__ Cpart, int N, int Kp) {
    __shared__ __align__(16) short As[128 * 64];
    __shared__ __align__(16) short Bs[128 * 64];
    int tid = threadIdx.x;
    int wv = tid >> 6, ln = tid & 63, g = ln >> 4, t = ln & 15;
    int wr = wv >> 1, wc = wv & 1;
    int rowBase = blockIdx.y * 128, colBase = blockIdx.x * 128;
    f32x4 acc[4][4] = {};
    int KT = Kp >> 6;
    int kt0 = (KT * blockIdx.z) / SPLITK, kt1 = (KT * (blockIdx.z + 1)) / SPLITK;
    for (int kt = kt0; kt < kt1; kt++) {
        int k0 = kt * 64;
        #pragma unroll
        for (int i = 0; i < 4; i++) {
            int idx = tid + 256 * i;
            int r = idx >> 3, c8 = idx & 7;
            int cs = (c8 ^ (r & 7)) * 8;
            gll16(A + (size_t)(rowBase + r) * Kp + k0 + cs, (char*)As + idx * 16);
            gll16(Bt + (size_t)(colBase + r) * Kp + k0 + cs, (char*)Bs + idx * 16);
        }
        __syncthreads();
        #pragma unroll
        for (int ks = 0; ks < 2; ks++) {
            bf16x8 af[4], bf[4];
            #pragma unroll
            for (int mi = 0; mi < 4; mi++) {
                int row = wr * 64 + mi * 16 + t;
                int kb = (ks * 64 + g * 16) ^ ((row & 7) << 4);
                af[mi] = *(const bf16x8*)((const char*)As + row * 128 + kb);
            }
            #pragma unroll
            for (int ni = 0; ni < 4; ni++) {
                int row = wc * 64 + ni * 16 + t;
                int kb = (ks * 64 + g * 16) ^ ((row & 7) << 4);
                bf[ni] = *(const bf16x8*)((const char*)Bs + row * 128 + kb);
            }
            #pragma unroll
            for (int mi = 0; mi < 4; mi++)
                #pragma unroll
                for (int ni = 0; ni < 4; ni++)
                    acc[mi][ni] = __builtin_amdgcn_mfma_f32_16x16x32_bf16(
                        af[mi], bf[ni], acc[mi][ni], 0, 0, 0);
        }
        __syncthreads();
    }
    #pragma unroll
    for (int mi = 0; mi < 4; mi++)
        #pragma unroll
        for (int ni = 0; ni < 4; ni++) {
            int col = colBase + wc * 64 + ni * 16 + t;
            #pragma unroll
            for (int r = 0; r < 4; r++) {
                int row = rowBase + wr * 64 + mi * 16 + g * 4 + r;
                if (OUT16) {
                    unsigned short* Cz = (unsigned short*)Cpart
                                       + (size_t)blockIdx.z * NTOK * N;
                    Cz[(size_t)row * N + col] = f2bf(acc[mi][ni][r]);
                } else {
                    float* Cz = (float*)Cpart + (size_t)blockIdx.z * NTOK * N;
                    Cz[(size_t)row * N + col] = acc[mi][ni][r];
                }
            }
        }
}

// ---------------- SwiGLU fused GEMM: 128x128, gll16 staging ----------------------
__global__ __launch_bounds__(256, 2) void gemm_swiglu_k(
        const short* __restrict__ A, const short* __restrict__ Ba,
        const short* __restrict__ Bg, const float* __restrict__ biasIn,
        unsigned short* __restrict__ actbf) {
    __shared__ __align__(16) short As[128 * 64];
    __shared__ __align__(16) short B1[128 * 64];
    __shared__ __align__(16) short B2[128 * 64];
    int tid = threadIdx.x;
    int wv = tid >> 6, ln = tid & 63, g = ln >> 4, t = ln & 15;
    int wr = wv >> 1, wc = wv & 1;
    int rowBase = blockIdx.y * 128, colBase = blockIdx.x * 128;
    f32x4 acca[4][4] = {};
    f32x4 accg[4][4] = {};
    for (int kt = 0; kt < 16; kt++) {
        int k0 = kt * 64;
        #pragma unroll
        for (int i = 0; i < 4; i++) {
            int idx = tid + 256 * i;
            int r = idx >> 3, c8 = idx & 7;
            int cs = (c8 ^ (r & 7)) * 8;
            gll16(A + (size_t)(rowBase + r) * 1024 + k0 + cs, (char*)As + idx * 16);
            gll16(Ba + (size_t)(colBase + r) * 1024 + k0 + cs, (char*)B1 + idx * 16);
            gll16(Bg + (size_t)(colBase + r) * 1024 + k0 + cs, (char*)B2 + idx * 16);
        }
        __syncthreads();
        #pragma unroll
        for (int ks = 0; ks < 2; ks++) {
            bf16x8 af[4], b1f[4], b2f[4];
            #pragma unroll
            for (int mi = 0; mi < 4; mi++) {
                int row = wr * 64 + mi * 16 + t;
                int kb = (ks * 64 + g * 16) ^ ((row & 7) << 4);
                af[mi] = *(const bf16x8*)((const char*)As + row * 128 + kb);
            }
            #pragma unroll
            for (int ni = 0; ni < 4; ni++) {
                int row = wc * 64 + ni * 16 + t;
                int kb = (ks * 64 + g * 16) ^ ((row & 7) << 4);
                b1f[ni] = *(const bf16x8*)((const char*)B1 + row * 128 + kb);
                b2f[ni] = *(const bf16x8*)((const char*)B2 + row * 128 + kb);
            }
            #pragma unroll
            for (int mi = 0; mi < 4; mi++)
                #pragma unroll
                for (int ni = 0; ni < 4; ni++) {
                    acca[mi][ni] = __builtin_amdgcn_mfma_f32_16x16x32_bf16(
                        af[mi], b1f[ni], acca[mi][ni], 0, 0, 0);
                    accg[mi][ni] = __builtin_amdgcn_mfma_f32_16x16x32_bf16(
                        af[mi], b2f[ni], accg[mi][ni], 0, 0, 0);
                }
        }
        __syncthreads();
    }
    const float rs2 = 0.70710678118654752f;
    #pragma unroll
    for (int mi = 0; mi < 4; mi++)
        #pragma unroll
        for (int ni = 0; ni < 4; ni++) {
            int col = colBase + wc * 64 + ni * 16 + t;
            if (col < FFHP) {
                float ba = (col < FFH) ? biasIn[col] : 0.f;
                float bg = (col < FFH) ? biasIn[FFH + col] : 0.f;
                #pragma unroll
                for (int r = 0; r < 4; r++) {
                    int row = rowBase + wr * 64 + mi * 16 + g * 4 + r;
                    unsigned short outv = 0;
                    if (col < FFH) {
                        float a_ = acca[mi][ni][r] + ba;
                        float g_ = accg[mi][ni][r] + bg;
                        float gel = 0.5f * g_ * (1.0f + erff(g_ * rs2));
                        outv = f2bf(a_ * gel);
                    }
                    actbf[(size_t)row * FFHP + col] = outv;
                }
            }
        }
}

// ---------------- RoPE on q,k -> bf16 (q pre-scaled) -----------------------------
__global__ void rope_lerp_k(const float* __restrict__ qkv,
                            unsigned short* __restrict__ qbf,
                            unsigned short* __restrict__ kbf) {
    int row = blockIdx.x;
    int tid = threadIdx.x;
    const float* qr = qkv + (size_t)row * 3072;
    #pragma unroll
    for (int it = 0; it < 2; it++) {
        int p = tid + 256 * it;
        int hh = p >> 5, pr = p & 31;
        float freq = expf(-(float)pr * (1.0f / 32.0f) * 9.2103403719762f);
        float ang = (float)row * freq;
        float s, c;
        sincosf(ang, &s, &c);
        int base = hh * 64 + pr * 2;
        float q0 = qr[base], q1 = qr[base + 1];
        float qa = q0 * c - q1 * s, qb = q1 * c + q0 * s;
        *(unsigned*)(qbf + (size_t)row * DIM + base) = pk2(qa * QK_SCALE, qb * QK_SCALE);
        float k0 = qr[1024 + base], k1 = qr[1024 + base + 1];
        *(unsigned*)(kbf + (size_t)row * DIM + base) = pk2(k0 * c - k1 * s, k1 * c + k0 * s);
    }
}

// ---------------- V: value-residual lerp + transpose -> Vtg[h][d][n] bf16 --------
__global__ __launch_bounds__(256) void vtrans_k(
        const float* __restrict__ qkv, float* __restrict__ fv,
        const float* __restrict__ mix, unsigned short* __restrict__ vtg, int layer) {
    __shared__ __align__(16) short T[64 * 64];
    int h = blockIdx.x, n0 = blockIdx.y * 64;
    int tid = threadIdx.x;
    #pragma unroll
    for (int it = 0; it < 2; it++) {
        int flat = tid + 256 * it;
        int n = flat >> 3, d0 = (flat & 7) * 8;
        int row = n0 + n;
        const float* src = qkv + (size_t)row * 3072 + 2048 + h * 64 + d0;
        float4 u0 = *(const float4*)src;
        float4 u1 = *(const float4*)(src + 4);
        float vals[8] = {u0.x, u0.y, u0.z, u0.w, u1.x, u1.y, u1.z, u1.w};
        float* fvp = fv + (size_t)row * DIM + h * 64 + d0;
        if (layer == 0) {
            *(float4*)fvp = u0;
            *(float4*)(fvp + 4) = u1;
        } else {
            float m = mix[row * HEADS + h];
            float4 f0 = *(const float4*)fvp;
            float4 f1 = *(const float4*)(fvp + 4);
            float fvv[8] = {f0.x, f0.y, f0.z, f0.w, f1.x, f1.y, f1.z, f1.w};
            #pragma unroll
            for (int e = 0; e < 8; e++) vals[e] += m * (fvv[e] - vals[e]);
        }
        #pragma unroll
        for (int e = 0; e < 8; e++) {
            int d = d0 + e;
            *(short*)((char*)T + d * 128 + ((2 * n) ^ ((d & 7) << 4))) = (short)f2bf(vals[e]);
        }
    }
    __syncthreads();
    #pragma unroll
    for (int it = 0; it < 2; it++) {
        int flat = tid + 256 * it;
        int d = flat >> 3, nn0 = (flat & 7) * 8;
        uint4 v = *(const uint4*)((const char*)T + d * 128 + ((2 * nn0) ^ ((d & 7) << 4)));
        *(uint4*)(vtg + (size_t)(h * 64 + d) * NTOK + n0 + nn0) = v;
    }
}

// ---------------- MFMA flash attention: one block per q-tile, heavy-first --------
// grid(16 h, 32 j') with j = 31-j' (heavy tiles dispatch first), 256 thr = 4 waves
// x 16 q rows. 512 blocks -> 2/CU. Same verified body: bf16 uint4 staging with
// swizzle folded into the global source column, K/V double-buffered with register
// prefetch, one barrier/chunk, P round-trip through per-wave LDS.
__global__ __launch_bounds__(256, 2) void attn_mfma_k(
        const unsigned short* __restrict__ Qbf, const unsigned short* __restrict__ Kbf,
        const unsigned short* __restrict__ Vtg, unsigned short* __restrict__ obf) {
    const int h = blockIdx.x;
    const int j = 31 - (int)blockIdx.y;
    const int tid = threadIdx.x;
    const int wv = tid >> 6, ln = tid & 63, g = ln >> 4, t = ln & 15;
    __shared__ __align__(16) short KsB[2][64 * 64];
    __shared__ __align__(16) short VtB[2][64 * 64];
    __shared__ __align__(16) short Plds[4 * 16 * 64];
    char* pw = (char*)(Plds + wv * 1024);

    const int sr = ln >> 3;
    const int scol = (ln & 7) ^ sr;                 // swizzle on global source
    const int sbyte0 = (wv * 16 + sr) * 128 + (ln & 7) * 16;
    const int sbyte1 = sbyte0 + 8 * 128;
    const unsigned short* kgl0 = Kbf + (size_t)(wv * 16 + sr) * DIM + h * 64 + scol * 8;
    const unsigned short* kgl1 = kgl0 + 8 * DIM;
    const unsigned short* vgl0 = Vtg + (size_t)(h * 64 + wv * 16 + sr) * NTOK + scol * 8;
    const unsigned short* vgl1 = vgl0 + 8 * NTOK;

    const int nch = ((j >> 1) + 1) * 2;
    const int qbase = j * 64;
    const unsigned short* qrow = Qbf + (size_t)(qbase + wv * 16 + t) * DIM + h * 64;
    bf16x8 qf0 = *(const bf16x8*)(qrow + 8 * g);
    bf16x8 qf1 = *(const bf16x8*)(qrow + 32 + 8 * g);
    f32x4 acc_o[4] = {};
    float mrun = -3.0e38f, lrun = 0.f;
    uint4 rk0 = *(const uint4*)kgl0;
    uint4 rk1 = *(const uint4*)kgl1;
    uint4 rv0 = *(const uint4*)vgl0;
    uint4 rv1 = *(const uint4*)vgl1;
    for (int kc = 0; kc < nch; kc++) {
        const int cur = kc & 1;
        *(uint4*)((char*)KsB[cur] + sbyte0) = rk0;
        *(uint4*)((char*)KsB[cur] + sbyte1) = rk1;
        *(uint4*)((char*)VtB[cur] + sbyte0) = rv0;
        *(uint4*)((char*)VtB[cur] + sbyte1) = rv1;
        if (kc + 1 < nch) {
            rk0 = *(const uint4*)(kgl0 + (size_t)(kc + 1) * 64 * DIM);
            rk1 = *(const uint4*)(kgl1 + (size_t)(kc + 1) * 64 * DIM);
            rv0 = *(const uint4*)(vgl0 + (kc + 1) * 64);
            rv1 = *(const uint4*)(vgl1 + (kc + 1) * 64);
        }
        __syncthreads();
        const char* Kc = (const char*)KsB[cur];
        const char* Vc = (const char*)VtB[cur];
        f32x4 accs[4] = {};
        #pragma unroll
        for (int kf = 0; kf < 4; kf++) {
            int row = kf * 16 + t;
            int kb0 = (g * 16) ^ ((row & 7) << 4);
            int kb1 = (64 + g * 16) ^ ((row & 7) << 4);
            bf16x8 k0 = *(const bf16x8*)(Kc + row * 128 + kb0);
            bf16x8 k1 = *(const bf16x8*)(Kc + row * 128 + kb1);
            accs[kf] = __builtin_amdgcn_mfma_f32_16x16x32_bf16(k0, qf0, accs[kf], 0, 0, 0);
            accs[kf] = __builtin_amdgcn_mfma_f32_16x16x32_bf16(k1, qf1, accs[kf], 0, 0, 0);
        }
        float pm = -3.0e38f;
        #pragma unroll
        for (int kf = 0; kf < 4; kf++)
            #pragma unroll
            for (int r = 0; r < 4; r++) pm = fmaxf(pm, accs[kf][r]);
        pm = fmaxf(pm, __shfl_xor(pm, 16));
        pm = fmaxf(pm, __shfl_xor(pm, 32));
        float mnew = fmaxf(mrun, pm);
        float corr = __expf(mrun - mnew);
        mrun = mnew;
        float psum = 0.f;
        #pragma unroll
        for (int kf = 0; kf < 4; kf++)
            #pragma unroll
            for (int r = 0; r < 4; r++) {
                float pv = __expf(accs[kf][r] - mnew);
                accs[kf][r] = pv;
                psum += pv;
            }
        psum += __shfl_xor(psum, 16);
        psum += __shfl_xor(psum, 32);
        lrun = lrun * corr + psum;
        #pragma unroll
        for (int kf = 0; kf < 4; kf++)
            #pragma unroll
            for (int rp = 0; rp < 4; rp += 2) {
                unsigned pv = pk2(accs[kf][rp], accs[kf][rp + 1]);
                int boff = (t * 128 + (16 * kf + 4 * g + rp) * 2) ^ ((t & 7) << 4);
                *(unsigned*)(pw + boff) = pv;
            }
        float cr[4];
        #pragma unroll
        for (int r = 0; r < 4; r++) cr[r] = __shfl(corr, g * 4 + r);
        #pragma unroll
        for (int ni = 0; ni < 4; ni++)
            #pragma unroll
            for (int r = 0; r < 4; r++) acc_o[ni][r] *= cr[r];
        #pragma unroll
        for (int ks = 0; ks < 2; ks++) {
            bf16x8 pa = *(const bf16x8*)(pw + ((t * 128 + 64 * ks + 16 * g) ^ ((t & 7) << 4)));
            #pragma unroll
            for (int ni = 0; ni < 4; ni++) {
                int row = ni * 16 + t;
                int vb = (64 * ks + 16 * g) ^ ((row & 7) << 4);
                bf16x8 vbf = *(const bf16x8*)(Vc + row * 128 + vb);
                acc_o[ni] = __builtin_amdgcn_mfma_f32_16x16x32_bf16(pa, vbf, acc_o[ni], 0, 0, 0);
            }
        }
    }
    float inv = 1.0f / lrun;
    float ir[4];
    #pragma unroll
    for (int r = 0; r < 4; r++) ir[r] = __shfl(inv, g * 4 + r);
    #pragma unroll
    for (int ni = 0; ni < 4; ni++)
        #pragma unroll
        for (int r = 0; r < 4; r++) {
            int row = qbase + wv * 16 + g * 4 + r;
            int col = h * 64 + ni * 16 + t;
            obf[(size_t)row * DIM + col] = f2bf(acc_o[ni][r] * ir[r]);
        }
}

// ---------------- driver ----------------------------------------------------------
extern "C" void kernel_launch(void* const* d_in, const int* in_sizes, int n_in,
                              void* d_out, int out_size, void* d_ws, size_t ws_size,
                              hipStream_t stream) {
    const float* tokens       = (const float*)d_in[0];
    const float* attn_norm_w  = (const float*)d_in[1];
    const float* w_qkv        = (const float*)d_in[2];
    const float* w_attn_out   = (const float*)d_in[3];
    const float* w_mix        = (const float*)d_in[4];
    const float* b_mix        = (const float*)d_in[5];
    const float* ff_norm_w    = (const float*)d_in[6];
    const float* b_ff_in      = (const float*)d_in[8];
    const float* w_ff_in      = (const float*)d_in[7];
    const float* w_ff_out     = (const float*)d_in[9];
    const float* b_ff_out     = (const float*)d_in[10];
    const float* final_norm_w = (const float*)d_in[11];

    char* p = (char*)d_ws;
    auto alloc = [&](size_t bytes) {
        char* r = p;
        p += (bytes + 255) & ~(size_t)255;
        return r;
    };
    short* wq_t  = (short*)alloc(4ull * 3072 * 1024 * 2);
    short* wo_t  = (short*)alloc(4ull * 1024 * 1024 * 2);
    short* wfa_t = (short*)alloc(4ull * FFNP * 1024 * 2);
    short* wfg_t = (short*)alloc(4ull * FFNP * 1024 * 2);
    short* wfo_t = (short*)alloc(4ull * 1024 * FFHP * 2);
    float* PART  = (float*)alloc((size_t)NTOK * 3072 * 4);  // union: qkv fp32 | out bf16 x4
    float* X     = (float*)alloc((size_t)NTOK * DIM * 4);
    float* FV    = (float*)alloc((size_t)NTOK * DIM * 4);
    float* MIX   = (float*)alloc((size_t)NTOK * HEADS * 4);
    short* Hbf   = (short*)alloc((size_t)NTOK * DIM * 2);
    short* Obf   = (short*)alloc((size_t)NTOK * DIM * 2);
    short* ACTbf = (short*)alloc((size_t)NTOK * FFHP * 2);
    unsigned short* Qbf = (unsigned short*)alloc((size_t)NTOK * DIM * 2);
    unsigned short* Kbf = (unsigned short*)alloc((size_t)NTOK * DIM * 2);
    unsigned short* Vtg = (unsigned short*)alloc((size_t)HEADS * 64 * NTOK * 2);
    float* QKVf = PART;                                   // [NTOK][3072] fp32
    unsigned short* PARTb = (unsigned short*)PART;        // [4][NTOK][1024] bf16

    // weight convert+transpose (bf16, [N][K]), batched over layers via blockIdx.z
    wconv_k<<<dim3(48, 16, 4), 256, 0, stream>>>(
        w_qkv, wq_t, 1024, 3072, 0, 3072, 1024, 3072,
        (size_t)1024 * 3072, (size_t)3072 * 1024);
    wconv_k<<<dim3(16, 16, 4), 256, 0, stream>>>(
        w_attn_out, wo_t, 1024, 1024, 0, 1024, 1024, 1024,
        (size_t)1024 * 1024, (size_t)1024 * 1024);
    wconv_k<<<dim3(44, 16, 4), 256, 0, stream>>>(
        w_ff_in, wfa_t, 1024, FFH, 0, FF2, 1024, FFNP,
        (size_t)1024 * FF2, (size_t)FFNP * 1024);
    wconv_k<<<dim3(44, 16, 4), 256, 0, stream>>>(
        w_ff_in, wfg_t, 1024, FFH, FFH, FF2, 1024, FFNP,
        (size_t)1024 * FF2, (size_t)FFNP * 1024);
    wconv_k<<<dim3(16, 43, 4), 256, 0, stream>>>(
        w_ff_out, wfo_t, FFH, 1024, 0, 1024, FFHP, 1024,
        (size_t)FFH * 1024, (size_t)1024 * FFHP);

    hipMemcpyAsync(X, tokens, (size_t)NTOK * DIM * sizeof(float),
                   hipMemcpyDeviceToDevice, stream);
    // layer-0 attention norm (layers 1-3 get theirs fused into ff_out reduce)
    rmsnorm_k<<<NTOK, 256, 0, stream>>>(X, attn_norm_w, (unsigned short*)Hbf);

    for (int i = 0; i < DEPTH; i++) {
        gemm_splitk_k<1, 0><<<dim3(24, 16, 1), 256, 0, stream>>>(
            Hbf, wq_t + (size_t)i * 3072 * 1024, QKVf, 3072, 1024);
        rope_lerp_k<<<NTOK, 256, 0, stream>>>(QKVf, Qbf, Kbf);
        vtrans_k<<<dim3(16, 32), 256, 0, stream>>>(QKVf, FV, MIX, Vtg, i);
        attn_mfma_k<<<dim3(16, 32), 256, 0, stream>>>(Qbf, Kbf, Vtg,
                                                      (unsigned short*)Obf);
        gemm_splitk_k<4, 1><<<dim3(8, 16, 4), 256, 0, stream>>>(
            Obf, wo_t + (size_t)i * 1024 * 1024, PARTb, 1024, 1024);
        rmsnorm_red_k<4, 0><<<NTOK, 256, 0, stream>>>(
            X, PARTb, nullptr, ff_norm_w + (size_t)i * DIM, X, nullptr,
            (unsigned short*)Hbf, nullptr, nullptr, nullptr);
        gemm_swiglu_k<<<dim3(22, 16), 256, 0, stream>>>(
            Hbf, wfa_t + (size_t)i * FFNP * 1024, wfg_t + (size_t)i * FFNP * 1024,
            b_ff_in + (size_t)i * FF2, (unsigned short*)ACTbf);
        gemm_splitk_k<4, 1><<<dim3(8, 16, 4), 256, 0, stream>>>(
            ACTbf, wfo_t + (size_t)i * 1024 * FFHP, PARTb, 1024, FFHP);
        if (i < DEPTH - 1) {
            // fused: residual+bias+norm for next layer's attention, plus that
            // layer's mix = sigmoid(h @ w_mix + b_mix) (value-residual gate)
            rmsnorm_red_k<4, 1><<<NTOK, 256, 0, stream>>>(
                X, PARTb, b_ff_out + (size_t)i * DIM, attn_norm_w + (size_t)(i + 1) * DIM,
                X, nullptr, (unsigned short*)Hbf,
                w_mix + (size_t)(i + 1) * DIM * HEADS, b_mix + (size_t)(i + 1) * HEADS,
                MIX);
        } else {
            rmsnorm_red_k<4, 0><<<NTOK, 256, 0, stream>>>(
                X, PARTb, b_ff_out + (size_t)i * DIM, final_norm_w,
                nullptr, (float*)d_out, nullptr, nullptr, nullptr, nullptr);
        }
    }
}

// Round 12
// 716.020 us; speedup vs baseline: 1.3490x; 1.0572x over previous
//
#include <hip/hip_runtime.h>
#include <hip/hip_bf16.h>

#define DIM   1024
#define NTOK  2048
#define HEADS 16
#define FFH   2730
#define FF2   5460
#define FFHP  2752   /* FFH padded to x64 */
#define FFNP  2816   /* FFH padded to x128 */
#define DEPTH 4
#define EPS_RMS 1.1920929e-07f
#define QK_SCALE 0.125f

typedef __attribute__((ext_vector_type(8))) short bf16x8;
typedef __attribute__((ext_vector_type(4))) float f32x4;

__device__ __forceinline__ unsigned short f2bf(float x) {
    unsigned u = __float_as_uint(x);
    u += 0x7fffu + ((u >> 16) & 1);          // RNE
    return (unsigned short)(u >> 16);
}
__device__ __forceinline__ float bf2f(unsigned short u) {
    return __uint_as_float((unsigned)u << 16);
}
__device__ __forceinline__ unsigned pk2(float a, float b) {
    unsigned ua = __float_as_uint(a); ua += 0x7fffu + ((ua >> 16) & 1);
    unsigned ub = __float_as_uint(b); ub += 0x7fffu + ((ub >> 16) & 1);
    return (ua >> 16) | (ub & 0xffff0000u);
}
__device__ __forceinline__ void unpk8(uint4 u, float* v) {
    v[0] = bf2f((unsigned short)u.x); v[1] = bf2f((unsigned short)(u.x >> 16));
    v[2] = bf2f((unsigned short)u.y); v[3] = bf2f((unsigned short)(u.y >> 16));
    v[4] = bf2f((unsigned short)u.z); v[5] = bf2f((unsigned short)(u.z >> 16));
    v[6] = bf2f((unsigned short)u.w); v[7] = bf2f((unsigned short)(u.w >> 16));
}
// async global->LDS, 16B per lane; dest must be wave-uniform base + lane*16
__device__ __forceinline__ void gll16(const void* g, void* l) {
    __builtin_amdgcn_global_load_lds(
        (const __attribute__((address_space(1))) void*)g,
        (__attribute__((address_space(3))) void*)l, 16, 0, 0);
}

// ---------------- RMSNorm (layer-0 attn norm): bf16 out --------------------------
__global__ void rmsnorm_k(const float* __restrict__ in, const float* __restrict__ w,
                          unsigned short* __restrict__ outbf) {
    int row = blockIdx.x;
    int tid = threadIdx.x;
    const float4* in4 = (const float4*)(in + (size_t)row * DIM);
    float4 v = in4[tid];
    float ss = v.x * v.x + v.y * v.y + v.z * v.z + v.w * v.w;
    #pragma unroll
    for (int off = 32; off > 0; off >>= 1) ss += __shfl_down(ss, off);
    __shared__ float lds[4];
    __shared__ float stot;
    int wid = tid >> 6, lane = tid & 63;
    if (lane == 0) lds[wid] = ss;
    __syncthreads();
    if (tid == 0) stot = lds[0] + lds[1] + lds[2] + lds[3];
    __syncthreads();
    float inv = 1.0f / sqrtf(stot * (1.0f / DIM) + EPS_RMS);
    const float4* w4 = (const float4*)w;
    float4 wv = w4[tid];
    float4 o;
    o.x = v.x * inv * wv.x; o.y = v.y * inv * wv.y;
    o.z = v.z * inv * wv.z; o.w = v.w * inv * wv.w;
    unsigned long long p = (unsigned long long)pk2(o.x, o.y)
                         | ((unsigned long long)pk2(o.z, o.w) << 32);
    ((unsigned long long*)(outbf + (size_t)row * DIM))[tid] = p;
}

// ---------------- fused residual-reduce (bf16 partials) + RMSNorm [+ mix] --------
template<int S, int DOMIX>
__global__ void rmsnorm_red_k(const float* __restrict__ X,
                              const unsigned short* __restrict__ P,
                              const float* __restrict__ bias, const float* __restrict__ w,
                              float* __restrict__ Xout, float* __restrict__ Hf,
                              unsigned short* __restrict__ Hbf,
                              const float* __restrict__ wm, const float* __restrict__ bm,
                              float* __restrict__ mix) {
    int row = blockIdx.x;
    int tid = threadIdx.x;
    float4 x = ((const float4*)(X + (size_t)row * DIM))[tid];
    #pragma unroll
    for (int s = 0; s < S; s++) {
        ushort4 p = ((const ushort4*)(P + (size_t)s * NTOK * DIM + (size_t)row * DIM))[tid];
        x.x += bf2f(p.x); x.y += bf2f(p.y); x.z += bf2f(p.z); x.w += bf2f(p.w);
    }
    if (bias) {
        float4 b = ((const float4*)bias)[tid];
        x.x += b.x; x.y += b.y; x.z += b.z; x.w += b.w;
    }
    float ss = x.x * x.x + x.y * x.y + x.z * x.z + x.w * x.w;
    #pragma unroll
    for (int off = 32; off > 0; off >>= 1) ss += __shfl_down(ss, off);
    __shared__ float lds[4];
    __shared__ float stot;
    int wid = tid >> 6, lane = tid & 63;
    if (lane == 0) lds[wid] = ss;
    __syncthreads();
    if (tid == 0) stot = lds[0] + lds[1] + lds[2] + lds[3];
    __syncthreads();
    float inv = 1.0f / sqrtf(stot * (1.0f / DIM) + EPS_RMS);
    if (Xout) ((float4*)(Xout + (size_t)row * DIM))[tid] = x;
    float4 wv = ((const float4*)w)[tid];
    float4 o;
    o.x = x.x * inv * wv.x; o.y = x.y * inv * wv.y;
    o.z = x.z * inv * wv.z; o.w = x.w * inv * wv.w;
    if (Hf) ((float4*)(Hf + (size_t)row * DIM))[tid] = o;
    if (Hbf) {
        unsigned long long p = (unsigned long long)pk2(o.x, o.y)
                             | ((unsigned long long)pk2(o.z, o.w) << 32);
        ((unsigned long long*)(Hbf + (size_t)row * DIM))[tid] = p;
    }
    if (DOMIX) {
        __shared__ float olds[1024];
        __shared__ float red[256];
        ((float4*)olds)[tid] = o;
        __syncthreads();
        int hh = tid & 15, kl = tid >> 4;
        float pm = 0.f;
        #pragma unroll
        for (int j = 0; j < 64; j++) {
            int k = kl + 16 * j;
            pm += olds[k] * wm[k * 16 + hh];
        }
        red[tid] = pm;
        __syncthreads();
        if (tid < 16) {
            float s = 0.f;
            #pragma unroll
            for (int k2 = 0; k2 < 16; k2++) s += red[k2 * 16 + tid];
            s += bm[tid];
            mix[row * HEADS + tid] = 1.0f / (1.0f + expf(-s));
        }
    }
}

// ---------------- weight transpose+convert (batched over layers via z) -----------
__global__ __launch_bounds__(256) void wconv_k(
        const float* __restrict__ W0, short* __restrict__ out0,
        int Ksrc, int Nsrc, int colOfs, int rowStride, int Kp, int Np,
        size_t wStride, size_t oStride) {
    const float* W = W0 + (size_t)blockIdx.z * wStride;
    short* out = out0 + (size_t)blockIdx.z * oStride;
    __shared__ float tile[64][65];
    int k0 = blockIdx.y * 64, n0 = blockIdx.x * 64;
    int tid = threadIdx.x;
    int c = tid & 63;
    #pragma unroll
    for (int kk4 = 0; kk4 < 16; kk4++) {
        int kk = kk4 * 4 + (tid >> 6);
        int gk = k0 + kk, gn = n0 + c;
        float v = 0.f;
        if (gk < Ksrc && gn < Nsrc) v = W[(size_t)gk * rowStride + colOfs + gn];
        tile[kk][c] = v;
    }
    __syncthreads();
    #pragma unroll
    for (int it = 0; it < 4; it++) {
        int flat = tid + 256 * it;
        int nn = flat >> 4, kg = (flat & 15) * 4;
        int gn = n0 + nn, gk = k0 + kg;
        if (gn < Np && gk < Kp) {
            short4 s;
            s.x = (short)f2bf(tile[kg + 0][nn]);
            s.y = (short)f2bf(tile[kg + 1][nn]);
            s.z = (short)f2bf(tile[kg + 2][nn]);
            s.w = (short)f2bf(tile[kg + 3][nn]);
            *(short4*)(out + (size_t)gn * Kp + gk) = s;
        }
    }
}

// ---------------- bf16 MFMA GEMM, split-K (single-buffered, gll16 staging) -------
template<int SPLITK, int OUT16>
__global__ __launch_bounds__(256, 4) void gemm_splitk_k(
        const short* __restrict__ A, const short* __restrict__ Bt,
        void* __restrict__ Cpart, int N, int Kp) {
    __shared__ __align__(16) short As[128 * 64];
    __shared__ __align__(16) short Bs[128 * 64];
    int tid = threadIdx.x;
    int wv = tid >> 6, ln = tid & 63, g = ln >> 4, t = ln & 15;
    int wr = wv >> 1, wc = wv & 1;
    int rowBase = blockIdx.y * 128, colBase = blockIdx.x * 128;
    f32x4 acc[4][4] = {};
    int KT = Kp >> 6;
    int kt0 = (KT * blockIdx.z) / SPLITK, kt1 = (KT * (blockIdx.z + 1)) / SPLITK;
    for (int kt = kt0; kt < kt1; kt++) {
        int k0 = kt * 64;
        #pragma unroll
        for (int i = 0; i < 4; i++) {
            int idx = tid + 256 * i;
            int r = idx >> 3, c8 = idx & 7;
            int cs = (c8 ^ (r & 7)) * 8;
            gll16(A + (size_t)(rowBase + r) * Kp + k0 + cs, (char*)As + idx * 16);
            gll16(Bt + (size_t)(colBase + r) * Kp + k0 + cs, (char*)Bs + idx * 16);
        }
        __syncthreads();
        #pragma unroll
        for (int ks = 0; ks < 2; ks++) {
            bf16x8 af[4], bf[4];
            #pragma unroll
            for (int mi = 0; mi < 4; mi++) {
                int row = wr * 64 + mi * 16 + t;
                int kb = (ks * 64 + g * 16) ^ ((row & 7) << 4);
                af[mi] = *(const bf16x8*)((const char*)As + row * 128 + kb);
            }
            #pragma unroll
            for (int ni = 0; ni < 4; ni++) {
                int row = wc * 64 + ni * 16 + t;
                int kb = (ks * 64 + g * 16) ^ ((row & 7) << 4);
                bf[ni] = *(const bf16x8*)((const char*)Bs + row * 128 + kb);
            }
            #pragma unroll
            for (int mi = 0; mi < 4; mi++)
                #pragma unroll
                for (int ni = 0; ni < 4; ni++)
                    acc[mi][ni] = __builtin_amdgcn_mfma_f32_16x16x32_bf16(
                        af[mi], bf[ni], acc[mi][ni], 0, 0, 0);
        }
        __syncthreads();
    }
    #pragma unroll
    for (int mi = 0; mi < 4; mi++)
        #pragma unroll
        for (int ni = 0; ni < 4; ni++) {
            int col = colBase + wc * 64 + ni * 16 + t;
            #pragma unroll
            for (int r = 0; r < 4; r++) {
                int row = rowBase + wr * 64 + mi * 16 + g * 4 + r;
                if (OUT16) {
                    unsigned short* Cz = (unsigned short*)Cpart
                                       + (size_t)blockIdx.z * NTOK * N;
                    Cz[(size_t)row * N + col] = f2bf(acc[mi][ni][r]);
                } else {
                    float* Cz = (float*)Cpart + (size_t)blockIdx.z * NTOK * N;
                    Cz[(size_t)row * N + col] = acc[mi][ni][r];
                }
            }
        }
}

// ---------------- SwiGLU fused GEMM: 128x64 tile, single-buffered, gll16 ---------
// act = (h@Wa+ba)*gelu(h@Wg+bg) -> bf16. 4 waves (2x2), per-wave 64x32 out.
// 32 KB LDS -> up to 4 blocks/CU; grid (43,16) = 688 blocks.
__global__ __launch_bounds__(256, 4) void gemm_swiglu_k(
        const short* __restrict__ A, const short* __restrict__ Ba,
        const short* __restrict__ Bg, const float* __restrict__ biasIn,
        unsigned short* __restrict__ actbf) {
    __shared__ __align__(16) short As[128 * 64];
    __shared__ __align__(16) short B1[64 * 64];
    __shared__ __align__(16) short B2[64 * 64];
    int tid = threadIdx.x;
    int wv = tid >> 6, ln = tid & 63, g = ln >> 4, t = ln & 15;
    int wr = wv >> 1, wc = wv & 1;
    int rowBase = blockIdx.y * 128, colBase = blockIdx.x * 64;
    f32x4 acca[4][2] = {};
    f32x4 accg[4][2] = {};
    for (int kt = 0; kt < 16; kt++) {
        int k0 = kt * 64;
        #pragma unroll
        for (int i = 0; i < 4; i++) {
            int idx = tid + 256 * i;
            int r = idx >> 3, c8 = idx & 7;
            int cs = (c8 ^ (r & 7)) * 8;
            gll16(A + (size_t)(rowBase + r) * 1024 + k0 + cs, (char*)As + idx * 16);
        }
        #pragma unroll
        for (int i = 0; i < 2; i++) {
            int idx = tid + 256 * i;
            int r = idx >> 3, c8 = idx & 7;
            int cs = (c8 ^ (r & 7)) * 8;
            gll16(Ba + (size_t)(colBase + r) * 1024 + k0 + cs, (char*)B1 + idx * 16);
            gll16(Bg + (size_t)(colBase + r) * 1024 + k0 + cs, (char*)B2 + idx * 16);
        }
        __syncthreads();
        #pragma unroll
        for (int ks = 0; ks < 2; ks++) {
            bf16x8 af[4], b1f[2], b2f[2];
            #pragma unroll
            for (int mi = 0; mi < 4; mi++) {
                int row = wr * 64 + mi * 16 + t;
                int kb = (ks * 64 + g * 16) ^ ((row & 7) << 4);
                af[mi] = *(const bf16x8*)((const char*)As + row * 128 + kb);
            }
            #pragma unroll
            for (int ni = 0; ni < 2; ni++) {
                int row = wc * 32 + ni * 16 + t;
                int kb = (ks * 64 + g * 16) ^ ((row & 7) << 4);
                b1f[ni] = *(const bf16x8*)((const char*)B1 + row * 128 + kb);
                b2f[ni] = *(const bf16x8*)((const char*)B2 + row * 128 + kb);
            }
            #pragma unroll
            for (int mi = 0; mi < 4; mi++)
                #pragma unroll
                for (int ni = 0; ni < 2; ni++) {
                    acca[mi][ni] = __builtin_amdgcn_mfma_f32_16x16x32_bf16(
                        af[mi], b1f[ni], acca[mi][ni], 0, 0, 0);
                    accg[mi][ni] = __builtin_amdgcn_mfma_f32_16x16x32_bf16(
                        af[mi], b2f[ni], accg[mi][ni], 0, 0, 0);
                }
        }
        __syncthreads();
    }
    const float rs2 = 0.70710678118654752f;
    #pragma unroll
    for (int mi = 0; mi < 4; mi++)
        #pragma unroll
        for (int ni = 0; ni < 2; ni++) {
            int col = colBase + wc * 32 + ni * 16 + t;
            float ba = (col < FFH) ? biasIn[col] : 0.f;
            float bg = (col < FFH) ? biasIn[FFH + col] : 0.f;
            #pragma unroll
            for (int r = 0; r < 4; r++) {
                int row = rowBase + wr * 64 + mi * 16 + g * 4 + r;
                unsigned short outv = 0;
                if (col < FFH) {
                    float a_ = acca[mi][ni][r] + ba;
                    float g_ = accg[mi][ni][r] + bg;
                    float gel = 0.5f * g_ * (1.0f + erff(g_ * rs2));
                    outv = f2bf(a_ * gel);
                }
                actbf[(size_t)row * FFHP + col] = outv;
            }
        }
}

// ---------------- RoPE on q,k (sums 2 bf16 qkv partial slices) -> bf16 -----------
__global__ void rope_lerp_k(const unsigned short* __restrict__ P,
                            unsigned short* __restrict__ qbf,
                            unsigned short* __restrict__ kbf) {
    int row = blockIdx.x;
    int tid = threadIdx.x;
    const unsigned short* s0 = P + (size_t)row * 3072;
    const unsigned short* s1 = s0 + (size_t)NTOK * 3072;
    #pragma unroll
    for (int it = 0; it < 2; it++) {
        int p = tid + 256 * it;
        int hh = p >> 5, pr = p & 31;
        float freq = expf(-(float)pr * (1.0f / 32.0f) * 9.2103403719762f);
        float ang = (float)row * freq;
        float s, c;
        sincosf(ang, &s, &c);
        int base = hh * 64 + pr * 2;
        unsigned a0 = *(const unsigned*)(s0 + base);
        unsigned a1 = *(const unsigned*)(s1 + base);
        float q0 = bf2f((unsigned short)a0) + bf2f((unsigned short)a1);
        float q1 = bf2f((unsigned short)(a0 >> 16)) + bf2f((unsigned short)(a1 >> 16));
        float qa = q0 * c - q1 * s, qb = q1 * c + q0 * s;
        *(unsigned*)(qbf + (size_t)row * DIM + base) = pk2(qa * QK_SCALE, qb * QK_SCALE);
        unsigned b0 = *(const unsigned*)(s0 + 1024 + base);
        unsigned b1 = *(const unsigned*)(s1 + 1024 + base);
        float k0 = bf2f((unsigned short)b0) + bf2f((unsigned short)b1);
        float k1 = bf2f((unsigned short)(b0 >> 16)) + bf2f((unsigned short)(b1 >> 16));
        *(unsigned*)(kbf + (size_t)row * DIM + base) = pk2(k0 * c - k1 * s, k1 * c + k0 * s);
    }
}

// ---------------- V: sum 2 bf16 partials + value-residual lerp + transpose -------
__global__ __launch_bounds__(256) void vtrans_k(
        const unsigned short* __restrict__ P, float* __restrict__ fv,
        const float* __restrict__ mix, unsigned short* __restrict__ vtg, int layer) {
    __shared__ __align__(16) short T[64 * 64];
    int h = blockIdx.x, n0 = blockIdx.y * 64;
    int tid = threadIdx.x;
    #pragma unroll
    for (int it = 0; it < 2; it++) {
        int flat = tid + 256 * it;
        int n = flat >> 3, d0 = (flat & 7) * 8;
        int row = n0 + n;
        const unsigned short* s0 = P + (size_t)row * 3072 + 2048 + h * 64 + d0;
        const unsigned short* s1 = s0 + (size_t)NTOK * 3072;
        float a[8], b[8], vals[8];
        unpk8(*(const uint4*)s0, a);
        unpk8(*(const uint4*)s1, b);
        #pragma unroll
        for (int e = 0; e < 8; e++) vals[e] = a[e] + b[e];
        float* fvp = fv + (size_t)row * DIM + h * 64 + d0;
        if (layer == 0) {
            *(float4*)fvp = make_float4(vals[0], vals[1], vals[2], vals[3]);
            *(float4*)(fvp + 4) = make_float4(vals[4], vals[5], vals[6], vals[7]);
        } else {
            float m = mix[row * HEADS + h];
            float4 f0 = *(const float4*)fvp;
            float4 f1 = *(const float4*)(fvp + 4);
            float fvv[8] = {f0.x, f0.y, f0.z, f0.w, f1.x, f1.y, f1.z, f1.w};
            #pragma unroll
            for (int e = 0; e < 8; e++) vals[e] += m * (fvv[e] - vals[e]);
        }
        #pragma unroll
        for (int e = 0; e < 8; e++) {
            int d = d0 + e;
            *(short*)((char*)T + d * 128 + ((2 * n) ^ ((d & 7) << 4))) = (short)f2bf(vals[e]);
        }
    }
    __syncthreads();
    #pragma unroll
    for (int it = 0; it < 2; it++) {
        int flat = tid + 256 * it;
        int d = flat >> 3, nn0 = (flat & 7) * 8;
        uint4 v = *(const uint4*)((const char*)T + d * 128 + ((2 * nn0) ^ ((d & 7) << 4)));
        *(uint4*)(vtg + (size_t)(h * 64 + d) * NTOK + n0 + nn0) = v;
    }
}

// ---------------- MFMA flash attention: one block per q-tile, heavy-first --------
__global__ __launch_bounds__(256, 2) void attn_mfma_k(
        const unsigned short* __restrict__ Qbf, const unsigned short* __restrict__ Kbf,
        const unsigned short* __restrict__ Vtg, unsigned short* __restrict__ obf) {
    const int h = blockIdx.x;
    const int j = 31 - (int)blockIdx.y;
    const int tid = threadIdx.x;
    const int wv = tid >> 6, ln = tid & 63, g = ln >> 4, t = ln & 15;
    __shared__ __align__(16) short KsB[2][64 * 64];
    __shared__ __align__(16) short VtB[2][64 * 64];
    __shared__ __align__(16) short Plds[4 * 16 * 64];
    char* pw = (char*)(Plds + wv * 1024);

    const int sr = ln >> 3;
    const int scol = (ln & 7) ^ sr;                 // swizzle on global source
    const int sbyte0 = (wv * 16 + sr) * 128 + (ln & 7) * 16;
    const int sbyte1 = sbyte0 + 8 * 128;
    const unsigned short* kgl0 = Kbf + (size_t)(wv * 16 + sr) * DIM + h * 64 + scol * 8;
    const unsigned short* kgl1 = kgl0 + 8 * DIM;
    const unsigned short* vgl0 = Vtg + (size_t)(h * 64 + wv * 16 + sr) * NTOK + scol * 8;
    const unsigned short* vgl1 = vgl0 + 8 * NTOK;

    const int nch = ((j >> 1) + 1) * 2;
    const int qbase = j * 64;
    const unsigned short* qrow = Qbf + (size_t)(qbase + wv * 16 + t) * DIM + h * 64;
    bf16x8 qf0 = *(const bf16x8*)(qrow + 8 * g);
    bf16x8 qf1 = *(const bf16x8*)(qrow + 32 + 8 * g);
    f32x4 acc_o[4] = {};
    float mrun = -3.0e38f, lrun = 0.f;
    uint4 rk0 = *(const uint4*)kgl0;
    uint4 rk1 = *(const uint4*)kgl1;
    uint4 rv0 = *(const uint4*)vgl0;
    uint4 rv1 = *(const uint4*)vgl1;
    for (int kc = 0; kc < nch; kc++) {
        const int cur = kc & 1;
        *(uint4*)((char*)KsB[cur] + sbyte0) = rk0;
        *(uint4*)((char*)KsB[cur] + sbyte1) = rk1;
        *(uint4*)((char*)VtB[cur] + sbyte0) = rv0;
        *(uint4*)((char*)VtB[cur] + sbyte1) = rv1;
        if (kc + 1 < nch) {
            rk0 = *(const uint4*)(kgl0 + (size_t)(kc + 1) * 64 * DIM);
            rk1 = *(const uint4*)(kgl1 + (size_t)(kc + 1) * 64 * DIM);
            rv0 = *(const uint4*)(vgl0 + (kc + 1) * 64);
            rv1 = *(const uint4*)(vgl1 + (kc + 1) * 64);
        }
        __syncthreads();
        const char* Kc = (const char*)KsB[cur];
        const char* Vc = (const char*)VtB[cur];
        f32x4 accs[4] = {};
        #pragma unroll
        for (int kf = 0; kf < 4; kf++) {
            int row = kf * 16 + t;
            int kb0 = (g * 16) ^ ((row & 7) << 4);
            int kb1 = (64 + g * 16) ^ ((row & 7) << 4);
            bf16x8 k0 = *(const bf16x8*)(Kc + row * 128 + kb0);
            bf16x8 k1 = *(const bf16x8*)(Kc + row * 128 + kb1);
            accs[kf] = __builtin_amdgcn_mfma_f32_16x16x32_bf16(k0, qf0, accs[kf], 0, 0, 0);
            accs[kf] = __builtin_amdgcn_mfma_f32_16x16x32_bf16(k1, qf1, accs[kf], 0, 0, 0);
        }
        float pm = -3.0e38f;
        #pragma unroll
        for (int kf = 0; kf < 4; kf++)
            #pragma unroll
            for (int r = 0; r < 4; r++) pm = fmaxf(pm, accs[kf][r]);
        pm = fmaxf(pm, __shfl_xor(pm, 16));
        pm = fmaxf(pm, __shfl_xor(pm, 32));
        float mnew = fmaxf(mrun, pm);
        float corr = __expf(mrun - mnew);
        mrun = mnew;
        float psum = 0.f;
        #pragma unroll
        for (int kf = 0; kf < 4; kf++)
            #pragma unroll
            for (int r = 0; r < 4; r++) {
                float pv = __expf(accs[kf][r] - mnew);
                accs[kf][r] = pv;
                psum += pv;
            }
        psum += __shfl_xor(psum, 16);
        psum += __shfl_xor(psum, 32);
        lrun = lrun * corr + psum;
        #pragma unroll
        for (int kf = 0; kf < 4; kf++)
            #pragma unroll
            for (int rp = 0; rp < 4; rp += 2) {
                unsigned pv = pk2(accs[kf][rp], accs[kf][rp + 1]);
                int boff = (t * 128 + (16 * kf + 4 * g + rp) * 2) ^ ((t & 7) << 4);
                *(unsigned*)(pw + boff) = pv;
            }
        float cr[4];
        #pragma unroll
        for (int r = 0; r < 4; r++) cr[r] = __shfl(corr, g * 4 + r);
        #pragma unroll
        for (int ni = 0; ni < 4; ni++)
            #pragma unroll
            for (int r = 0; r < 4; r++) acc_o[ni][r] *= cr[r];
        #pragma unroll
        for (int ks = 0; ks < 2; ks++) {
            bf16x8 pa = *(const bf16x8*)(pw + ((t * 128 + 64 * ks + 16 * g) ^ ((t & 7) << 4)));
            #pragma unroll
            for (int ni = 0; ni < 4; ni++) {
                int row = ni * 16 + t;
                int vb = (64 * ks + 16 * g) ^ ((row & 7) << 4);
                bf16x8 vbf = *(const bf16x8*)(Vc + row * 128 + vb);
                acc_o[ni] = __builtin_amdgcn_mfma_f32_16x16x32_bf16(pa, vbf, acc_o[ni], 0, 0, 0);
            }
        }
    }
    float inv = 1.0f / lrun;
    float ir[4];
    #pragma unroll
    for (int r = 0; r < 4; r++) ir[r] = __shfl(inv, g * 4 + r);
    #pragma unroll
    for (int ni = 0; ni < 4; ni++)
        #pragma unroll
        for (int r = 0; r < 4; r++) {
            int row = qbase + wv * 16 + g * 4 + r;
            int col = h * 64 + ni * 16 + t;
            obf[(size_t)row * DIM + col] = f2bf(acc_o[ni][r] * ir[r]);
        }
}

// ---------------- driver ----------------------------------------------------------
extern "C" void kernel_launch(void* const* d_in, const int* in_sizes, int n_in,
                              void* d_out, int out_size, void* d_ws, size_t ws_size,
                              hipStream_t stream) {
    const float* tokens       = (const float*)d_in[0];
    const float* attn_norm_w  = (const float*)d_in[1];
    const float* w_qkv        = (const float*)d_in[2];
    const float* w_attn_out   = (const float*)d_in[3];
    const float* w_mix        = (const float*)d_in[4];
    const float* b_mix        = (const float*)d_in[5];
    const float* ff_norm_w    = (const float*)d_in[6];
    const float* w_ff_in      = (const float*)d_in[7];
    const float* b_ff_in      = (const float*)d_in[8];
    const float* w_ff_out     = (const float*)d_in[9];
    const float* b_ff_out     = (const float*)d_in[10];
    const float* final_norm_w = (const float*)d_in[11];

    char* p = (char*)d_ws;
    auto alloc = [&](size_t bytes) {
        char* r = p;
        p += (bytes + 255) & ~(size_t)255;
        return r;
    };
    short* wq_t  = (short*)alloc(4ull * 3072 * 1024 * 2);
    short* wo_t  = (short*)alloc(4ull * 1024 * 1024 * 2);
    short* wfa_t = (short*)alloc(4ull * FFNP * 1024 * 2);
    short* wfg_t = (short*)alloc(4ull * FFNP * 1024 * 2);
    short* wfo_t = (short*)alloc(4ull * 1024 * FFHP * 2);
    float* PART  = (float*)alloc((size_t)NTOK * 3072 * 4);  // union: qkv bf16 x2 | out bf16 x4
    float* X     = (float*)alloc((size_t)NTOK * DIM * 4);
    float* FV    = (float*)alloc((size_t)NTOK * DIM * 4);
    float* MIX   = (float*)alloc((size_t)NTOK * HEADS * 4);
    short* Hbf   = (short*)alloc((size_t)NTOK * DIM * 2);
    short* Obf   = (short*)alloc((size_t)NTOK * DIM * 2);
    short* ACTbf = (short*)alloc((size_t)NTOK * FFHP * 2);
    unsigned short* Qbf = (unsigned short*)alloc((size_t)NTOK * DIM * 2);
    unsigned short* Kbf = (unsigned short*)alloc((size_t)NTOK * DIM * 2);
    unsigned short* Vtg = (unsigned short*)alloc((size_t)HEADS * 64 * NTOK * 2);
    unsigned short* PARTq = (unsigned short*)PART;        // [2][NTOK][3072] bf16
    unsigned short* PARTb = (unsigned short*)PART;        // [4][NTOK][1024] bf16

    // weight convert+transpose (bf16, [N][K]), batched over layers via blockIdx.z
    wconv_k<<<dim3(48, 16, 4), 256, 0, stream>>>(
        w_qkv, wq_t, 1024, 3072, 0, 3072, 1024, 3072,
        (size_t)1024 * 3072, (size_t)3072 * 1024);
    wconv_k<<<dim3(16, 16, 4), 256, 0, stream>>>(
        w_attn_out, wo_t, 1024, 1024, 0, 1024, 1024, 1024,
        (size_t)1024 * 1024, (size_t)1024 * 1024);
    wconv_k<<<dim3(44, 16, 4), 256, 0, stream>>>(
        w_ff_in, wfa_t, 1024, FFH, 0, FF2, 1024, FFNP,
        (size_t)1024 * FF2, (size_t)FFNP * 1024);
    wconv_k<<<dim3(44, 16, 4), 256, 0, stream>>>(
        w_ff_in, wfg_t, 1024, FFH, FFH, FF2, 1024, FFNP,
        (size_t)1024 * FF2, (size_t)FFNP * 1024);
    wconv_k<<<dim3(16, 43, 4), 256, 0, stream>>>(
        w_ff_out, wfo_t, FFH, 1024, 0, 1024, FFHP, 1024,
        (size_t)FFH * 1024, (size_t)1024 * FFHP);

    hipMemcpyAsync(X, tokens, (size_t)NTOK * DIM * sizeof(float),
                   hipMemcpyDeviceToDevice, stream);
    // layer-0 attention norm (layers 1-3 get theirs fused into ff_out reduce)
    rmsnorm_k<<<NTOK, 256, 0, stream>>>(X, attn_norm_w, (unsigned short*)Hbf);

    for (int i = 0; i < DEPTH; i++) {
        gemm_splitk_k<2, 1><<<dim3(24, 16, 2), 256, 0, stream>>>(
            Hbf, wq_t + (size_t)i * 3072 * 1024, PARTq, 3072, 1024);
        rope_lerp_k<<<NTOK, 256, 0, stream>>>(PARTq, Qbf, Kbf);
        vtrans_k<<<dim3(16, 32), 256, 0, stream>>>(PARTq, FV, MIX, Vtg, i);
        attn_mfma_k<<<dim3(16, 32), 256, 0, stream>>>(Qbf, Kbf, Vtg,
                                                      (unsigned short*)Obf);
        gemm_splitk_k<4, 1><<<dim3(8, 16, 4), 256, 0, stream>>>(
            Obf, wo_t + (size_t)i * 1024 * 1024, PARTb, 1024, 1024);
        rmsnorm_red_k<4, 0><<<NTOK, 256, 0, stream>>>(
            X, PARTb, nullptr, ff_norm_w + (size_t)i * DIM, X, nullptr,
            (unsigned short*)Hbf, nullptr, nullptr, nullptr);
        gemm_swiglu_k<<<dim3(43, 16), 256, 0, stream>>>(
            Hbf, wfa_t + (size_t)i * FFNP * 1024, wfg_t + (size_t)i * FFNP * 1024,
            b_ff_in + (size_t)i * FF2, (unsigned short*)ACTbf);
        gemm_splitk_k<4, 1><<<dim3(8, 16, 4), 256, 0, stream>>>(
            ACTbf, wfo_t + (size_t)i * 1024 * FFHP, PARTb, 1024, FFHP);
        if (i < DEPTH - 1) {
            rmsnorm_red_k<4, 1><<<NTOK, 256, 0, stream>>>(
                X, PARTb, b_ff_out + (size_t)i * DIM, attn_norm_w + (size_t)(i + 1) * DIM,
                X, nullptr, (unsigned short*)Hbf,
                w_mix + (size_t)(i + 1) * DIM * HEADS, b_mix + (size_t)(i + 1) * HEADS,
                MIX);
        } else {
            rmsnorm_red_k<4, 0><<<NTOK, 256, 0, stream>>>(
                X, PARTb, b_ff_out + (size_t)i * DIM, final_norm_w,
                nullptr, (float*)d_out, nullptr, nullptr, nullptr, nullptr);
        }
    }
}

// Round 13
// 712.190 us; speedup vs baseline: 1.3562x; 1.0054x over previous
//
#include <hip/hip_runtime.h>
#include <hip/hip_bf16.h>

#define DIM   1024
#define NTOK  2048
#define HEADS 16
#define FFH   2730
#define FF2   5460
#define FFHP  2752   /* FFH padded to x64 */
#define FFNP  2816   /* FFH padded to x128 */
#define DEPTH 4
#define EPS_RMS 1.1920929e-07f
#define QK_SCALE 0.125f

typedef __attribute__((ext_vector_type(8))) short bf16x8;
typedef __attribute__((ext_vector_type(4))) float f32x4;

__device__ __forceinline__ unsigned short f2bf(float x) {
    unsigned u = __float_as_uint(x);
    u += 0x7fffu + ((u >> 16) & 1);          // RNE
    return (unsigned short)(u >> 16);
}
__device__ __forceinline__ float bf2f(unsigned short u) {
    return __uint_as_float((unsigned)u << 16);
}
__device__ __forceinline__ unsigned pk2(float a, float b) {
    unsigned ua = __float_as_uint(a); ua += 0x7fffu + ((ua >> 16) & 1);
    unsigned ub = __float_as_uint(b); ub += 0x7fffu + ((ub >> 16) & 1);
    return (ua >> 16) | (ub & 0xffff0000u);
}
__device__ __forceinline__ void unpk8(uint4 u, float* v) {
    v[0] = bf2f((unsigned short)u.x); v[1] = bf2f((unsigned short)(u.x >> 16));
    v[2] = bf2f((unsigned short)u.y); v[3] = bf2f((unsigned short)(u.y >> 16));
    v[4] = bf2f((unsigned short)u.z); v[5] = bf2f((unsigned short)(u.z >> 16));
    v[6] = bf2f((unsigned short)u.w); v[7] = bf2f((unsigned short)(u.w >> 16));
}
// async global->LDS, 16B per lane; dest must be wave-uniform base + lane*16
__device__ __forceinline__ void gll16(const void* g, void* l) {
    __builtin_amdgcn_global_load_lds(
        (const __attribute__((address_space(1))) void*)g,
        (__attribute__((address_space(3))) void*)l, 16, 0, 0);
}

// ---------------- RMSNorm (layer-0 attn norm): bf16 out --------------------------
__global__ void rmsnorm_k(const float* __restrict__ in, const float* __restrict__ w,
                          unsigned short* __restrict__ outbf) {
    int row = blockIdx.x;
    int tid = threadIdx.x;
    const float4* in4 = (const float4*)(in + (size_t)row * DIM);
    float4 v = in4[tid];
    float ss = v.x * v.x + v.y * v.y + v.z * v.z + v.w * v.w;
    #pragma unroll
    for (int off = 32; off > 0; off >>= 1) ss += __shfl_down(ss, off);
    __shared__ float lds[4];
    __shared__ float stot;
    int wid = tid >> 6, lane = tid & 63;
    if (lane == 0) lds[wid] = ss;
    __syncthreads();
    if (tid == 0) stot = lds[0] + lds[1] + lds[2] + lds[3];
    __syncthreads();
    float inv = 1.0f / sqrtf(stot * (1.0f / DIM) + EPS_RMS);
    const float4* w4 = (const float4*)w;
    float4 wv = w4[tid];
    float4 o;
    o.x = v.x * inv * wv.x; o.y = v.y * inv * wv.y;
    o.z = v.z * inv * wv.z; o.w = v.w * inv * wv.w;
    unsigned long long p = (unsigned long long)pk2(o.x, o.y)
                         | ((unsigned long long)pk2(o.z, o.w) << 32);
    ((unsigned long long*)(outbf + (size_t)row * DIM))[tid] = p;
}

// ---------------- fused residual-reduce (bf16 partials) + RMSNorm [+ mix] --------
template<int S, int DOMIX>
__global__ void rmsnorm_red_k(const float* __restrict__ X,
                              const unsigned short* __restrict__ P,
                              const float* __restrict__ bias, const float* __restrict__ w,
                              float* __restrict__ Xout, float* __restrict__ Hf,
                              unsigned short* __restrict__ Hbf,
                              const float* __restrict__ wm, const float* __restrict__ bm,
                              float* __restrict__ mix) {
    int row = blockIdx.x;
    int tid = threadIdx.x;
    float4 x = ((const float4*)(X + (size_t)row * DIM))[tid];
    #pragma unroll
    for (int s = 0; s < S; s++) {
        ushort4 p = ((const ushort4*)(P + (size_t)s * NTOK * DIM + (size_t)row * DIM))[tid];
        x.x += bf2f(p.x); x.y += bf2f(p.y); x.z += bf2f(p.z); x.w += bf2f(p.w);
    }
    if (bias) {
        float4 b = ((const float4*)bias)[tid];
        x.x += b.x; x.y += b.y; x.z += b.z; x.w += b.w;
    }
    float ss = x.x * x.x + x.y * x.y + x.z * x.z + x.w * x.w;
    #pragma unroll
    for (int off = 32; off > 0; off >>= 1) ss += __shfl_down(ss, off);
    __shared__ float lds[4];
    __shared__ float stot;
    int wid = tid >> 6, lane = tid & 63;
    if (lane == 0) lds[wid] = ss;
    __syncthreads();
    if (tid == 0) stot = lds[0] + lds[1] + lds[2] + lds[3];
    __syncthreads();
    float inv = 1.0f / sqrtf(stot * (1.0f / DIM) + EPS_RMS);
    if (Xout) ((float4*)(Xout + (size_t)row * DIM))[tid] = x;
    float4 wv = ((const float4*)w)[tid];
    float4 o;
    o.x = x.x * inv * wv.x; o.y = x.y * inv * wv.y;
    o.z = x.z * inv * wv.z; o.w = x.w * inv * wv.w;
    if (Hf) ((float4*)(Hf + (size_t)row * DIM))[tid] = o;
    if (Hbf) {
        unsigned long long p = (unsigned long long)pk2(o.x, o.y)
                             | ((unsigned long long)pk2(o.z, o.w) << 32);
        ((unsigned long long*)(Hbf + (size_t)row * DIM))[tid] = p;
    }
    if (DOMIX) {
        __shared__ float olds[1024];
        __shared__ float red[256];
        ((float4*)olds)[tid] = o;
        __syncthreads();
        int hh = tid & 15, kl = tid >> 4;
        float pm = 0.f;
        #pragma unroll
        for (int j = 0; j < 64; j++) {
            int k = kl + 16 * j;
            pm += olds[k] * wm[k * 16 + hh];
        }
        red[tid] = pm;
        __syncthreads();
        if (tid < 16) {
            float s = 0.f;
            #pragma unroll
            for (int k2 = 0; k2 < 16; k2++) s += red[k2 * 16 + tid];
            s += bm[tid];
            mix[row * HEADS + tid] = 1.0f / (1.0f + expf(-s));
        }
    }
}

// ---------------- weight transpose+convert (batched over layers via z) -----------
__global__ __launch_bounds__(256) void wconv_k(
        const float* __restrict__ W0, short* __restrict__ out0,
        int Ksrc, int Nsrc, int colOfs, int rowStride, int Kp, int Np,
        size_t wStride, size_t oStride) {
    const float* W = W0 + (size_t)blockIdx.z * wStride;
    short* out = out0 + (size_t)blockIdx.z * oStride;
    __shared__ float tile[64][65];
    int k0 = blockIdx.y * 64, n0 = blockIdx.x * 64;
    int tid = threadIdx.x;
    int c = tid & 63;
    #pragma unroll
    for (int kk4 = 0; kk4 < 16; kk4++) {
        int kk = kk4 * 4 + (tid >> 6);
        int gk = k0 + kk, gn = n0 + c;
        float v = 0.f;
        if (gk < Ksrc && gn < Nsrc) v = W[(size_t)gk * rowStride + colOfs + gn];
        tile[kk][c] = v;
    }
    __syncthreads();
    #pragma unroll
    for (int it = 0; it < 4; it++) {
        int flat = tid + 256 * it;
        int nn = flat >> 4, kg = (flat & 15) * 4;
        int gn = n0 + nn, gk = k0 + kg;
        if (gn < Np && gk < Kp) {
            short4 s;
            s.x = (short)f2bf(tile[kg + 0][nn]);
            s.y = (short)f2bf(tile[kg + 1][nn]);
            s.z = (short)f2bf(tile[kg + 2][nn]);
            s.w = (short)f2bf(tile[kg + 3][nn]);
            *(short4*)(out + (size_t)gn * Kp + gk) = s;
        }
    }
}

// ---------------- bf16 MFMA GEMM, split-K (single-buffered, gll16 staging) -------
template<int SPLITK, int OUT16>
__global__ __launch_bounds__(256, 4) void gemm_splitk_k(
        const short* __restrict__ A, const short* __restrict__ Bt,
        void* __restrict__ Cpart, int N, int Kp) {
    __shared__ __align__(16) short As[128 * 64];
    __shared__ __align__(16) short Bs[128 * 64];
    int tid = threadIdx.x;
    int wv = tid >> 6, ln = tid & 63, g = ln >> 4, t = ln & 15;
    int wr = wv >> 1, wc = wv & 1;
    int rowBase = blockIdx.y * 128, colBase = blockIdx.x * 128;
    f32x4 acc[4][4] = {};
    int KT = Kp >> 6;
    int kt0 = (KT * blockIdx.z) / SPLITK, kt1 = (KT * (blockIdx.z + 1)) / SPLITK;
    for (int kt = kt0; kt < kt1; kt++) {
        int k0 = kt * 64;
        #pragma unroll
        for (int i = 0; i < 4; i++) {
            int idx = tid + 256 * i;
            int r = idx >> 3, c8 = idx & 7;
            int cs = (c8 ^ (r & 7)) * 8;
            gll16(A + (size_t)(rowBase + r) * Kp + k0 + cs, (char*)As + idx * 16);
            gll16(Bt + (size_t)(colBase + r) * Kp + k0 + cs, (char*)Bs + idx * 16);
        }
        __syncthreads();
        #pragma unroll
        for (int ks = 0; ks < 2; ks++) {
            bf16x8 af[4], bf[4];
            #pragma unroll
            for (int mi = 0; mi < 4; mi++) {
                int row = wr * 64 + mi * 16 + t;
                int kb = (ks * 64 + g * 16) ^ ((row & 7) << 4);
                af[mi] = *(const bf16x8*)((const char*)As + row * 128 + kb);
            }
            #pragma unroll
            for (int ni = 0; ni < 4; ni++) {
                int row = wc * 64 + ni * 16 + t;
                int kb = (ks * 64 + g * 16) ^ ((row & 7) << 4);
                bf[ni] = *(const bf16x8*)((const char*)Bs + row * 128 + kb);
            }
            #pragma unroll
            for (int mi = 0; mi < 4; mi++)
                #pragma unroll
                for (int ni = 0; ni < 4; ni++)
                    acc[mi][ni] = __builtin_amdgcn_mfma_f32_16x16x32_bf16(
                        af[mi], bf[ni], acc[mi][ni], 0, 0, 0);
        }
        __syncthreads();
    }
    #pragma unroll
    for (int mi = 0; mi < 4; mi++)
        #pragma unroll
        for (int ni = 0; ni < 4; ni++) {
            int col = colBase + wc * 64 + ni * 16 + t;
            #pragma unroll
            for (int r = 0; r < 4; r++) {
                int row = rowBase + wr * 64 + mi * 16 + g * 4 + r;
                if (OUT16) {
                    unsigned short* Cz = (unsigned short*)Cpart
                                       + (size_t)blockIdx.z * NTOK * N;
                    Cz[(size_t)row * N + col] = f2bf(acc[mi][ni][r]);
                } else {
                    float* Cz = (float*)Cpart + (size_t)blockIdx.z * NTOK * N;
                    Cz[(size_t)row * N + col] = acc[mi][ni][r];
                }
            }
        }
}

// ---------------- SwiGLU fused GEMM: 128x64 tile, single-buffered, gll16 ---------
__global__ __launch_bounds__(256, 4) void gemm_swiglu_k(
        const short* __restrict__ A, const short* __restrict__ Ba,
        const short* __restrict__ Bg, const float* __restrict__ biasIn,
        unsigned short* __restrict__ actbf) {
    __shared__ __align__(16) short As[128 * 64];
    __shared__ __align__(16) short B1[64 * 64];
    __shared__ __align__(16) short B2[64 * 64];
    int tid = threadIdx.x;
    int wv = tid >> 6, ln = tid & 63, g = ln >> 4, t = ln & 15;
    int wr = wv >> 1, wc = wv & 1;
    int rowBase = blockIdx.y * 128, colBase = blockIdx.x * 64;
    f32x4 acca[4][2] = {};
    f32x4 accg[4][2] = {};
    for (int kt = 0; kt < 16; kt++) {
        int k0 = kt * 64;
        #pragma unroll
        for (int i = 0; i < 4; i++) {
            int idx = tid + 256 * i;
            int r = idx >> 3, c8 = idx & 7;
            int cs = (c8 ^ (r & 7)) * 8;
            gll16(A + (size_t)(rowBase + r) * 1024 + k0 + cs, (char*)As + idx * 16);
        }
        #pragma unroll
        for (int i = 0; i < 2; i++) {
            int idx = tid + 256 * i;
            int r = idx >> 3, c8 = idx & 7;
            int cs = (c8 ^ (r & 7)) * 8;
            gll16(Ba + (size_t)(colBase + r) * 1024 + k0 + cs, (char*)B1 + idx * 16);
            gll16(Bg + (size_t)(colBase + r) * 1024 + k0 + cs, (char*)B2 + idx * 16);
        }
        __syncthreads();
        #pragma unroll
        for (int ks = 0; ks < 2; ks++) {
            bf16x8 af[4], b1f[2], b2f[2];
            #pragma unroll
            for (int mi = 0; mi < 4; mi++) {
                int row = wr * 64 + mi * 16 + t;
                int kb = (ks * 64 + g * 16) ^ ((row & 7) << 4);
                af[mi] = *(const bf16x8*)((const char*)As + row * 128 + kb);
            }
            #pragma unroll
            for (int ni = 0; ni < 2; ni++) {
                int row = wc * 32 + ni * 16 + t;
                int kb = (ks * 64 + g * 16) ^ ((row & 7) << 4);
                b1f[ni] = *(const bf16x8*)((const char*)B1 + row * 128 + kb);
                b2f[ni] = *(const bf16x8*)((const char*)B2 + row * 128 + kb);
            }
            #pragma unroll
            for (int mi = 0; mi < 4; mi++)
                #pragma unroll
                for (int ni = 0; ni < 2; ni++) {
                    acca[mi][ni] = __builtin_amdgcn_mfma_f32_16x16x32_bf16(
                        af[mi], b1f[ni], acca[mi][ni], 0, 0, 0);
                    accg[mi][ni] = __builtin_amdgcn_mfma_f32_16x16x32_bf16(
                        af[mi], b2f[ni], accg[mi][ni], 0, 0, 0);
                }
        }
        __syncthreads();
    }
    const float rs2 = 0.70710678118654752f;
    #pragma unroll
    for (int mi = 0; mi < 4; mi++)
        #pragma unroll
        for (int ni = 0; ni < 2; ni++) {
            int col = colBase + wc * 32 + ni * 16 + t;
            float ba = (col < FFH) ? biasIn[col] : 0.f;
            float bg = (col < FFH) ? biasIn[FFH + col] : 0.f;
            #pragma unroll
            for (int r = 0; r < 4; r++) {
                int row = rowBase + wr * 64 + mi * 16 + g * 4 + r;
                unsigned short outv = 0;
                if (col < FFH) {
                    float a_ = acca[mi][ni][r] + ba;
                    float g_ = accg[mi][ni][r] + bg;
                    float gel = 0.5f * g_ * (1.0f + erff(g_ * rs2));
                    outv = f2bf(a_ * gel);
                }
                actbf[(size_t)row * FFHP + col] = outv;
            }
        }
}

// ---------------- qkv post: RoPE(q,k) + V lerp/transpose, merged -----------------
// grid (16 h, 32 nt), 256 thr. Handles rows [nt*64, nt*64+64) of head h:
// part 1 ropes q,k (identical per-(row,pr) sincos/order as before); part 2 is the
// verified vtrans body (sum 2 bf16 partials, value-residual lerp, LDS transpose).
__global__ __launch_bounds__(256) void qkvpost_k(
        const unsigned short* __restrict__ P,
        unsigned short* __restrict__ qbf, unsigned short* __restrict__ kbf,
        float* __restrict__ fv, const float* __restrict__ mix,
        unsigned short* __restrict__ vtg, int layer) {
    int h = blockIdx.x, n0 = blockIdx.y * 64;
    int tid = threadIdx.x;
    const unsigned short* P1 = P + (size_t)NTOK * 3072;
    // ---- rope q,k ----
    #pragma unroll
    for (int it = 0; it < 8; it++) {
        int item = tid + 256 * it;
        int rl = item >> 5, pr = item & 31;
        int row = n0 + rl;
        float freq = expf(-(float)pr * (1.0f / 32.0f) * 9.2103403719762f);
        float ang = (float)row * freq;
        float s, c;
        sincosf(ang, &s, &c);
        size_t off = (size_t)row * 3072 + h * 64 + pr * 2;
        unsigned a0 = *(const unsigned*)(P + off);
        unsigned a1 = *(const unsigned*)(P1 + off);
        float q0 = bf2f((unsigned short)a0) + bf2f((unsigned short)a1);
        float q1 = bf2f((unsigned short)(a0 >> 16)) + bf2f((unsigned short)(a1 >> 16));
        *(unsigned*)(qbf + (size_t)row * DIM + h * 64 + pr * 2) =
            pk2((q0 * c - q1 * s) * QK_SCALE, (q1 * c + q0 * s) * QK_SCALE);
        unsigned b0 = *(const unsigned*)(P + off + 1024);
        unsigned b1 = *(const unsigned*)(P1 + off + 1024);
        float k0 = bf2f((unsigned short)b0) + bf2f((unsigned short)b1);
        float k1 = bf2f((unsigned short)(b0 >> 16)) + bf2f((unsigned short)(b1 >> 16));
        *(unsigned*)(kbf + (size_t)row * DIM + h * 64 + pr * 2) =
            pk2(k0 * c - k1 * s, k1 * c + k0 * s);
    }
    // ---- V: sum partials + value-residual lerp + transpose ----
    __shared__ __align__(16) short T[64 * 64];
    #pragma unroll
    for (int it = 0; it < 2; it++) {
        int flat = tid + 256 * it;
        int n = flat >> 3, d0 = (flat & 7) * 8;
        int row = n0 + n;
        const unsigned short* s0 = P + (size_t)row * 3072 + 2048 + h * 64 + d0;
        const unsigned short* s1 = s0 + (size_t)NTOK * 3072;
        float a[8], b[8], vals[8];
        unpk8(*(const uint4*)s0, a);
        unpk8(*(const uint4*)s1, b);
        #pragma unroll
        for (int e = 0; e < 8; e++) vals[e] = a[e] + b[e];
        float* fvp = fv + (size_t)row * DIM + h * 64 + d0;
        if (layer == 0) {
            *(float4*)fvp = make_float4(vals[0], vals[1], vals[2], vals[3]);
            *(float4*)(fvp + 4) = make_float4(vals[4], vals[5], vals[6], vals[7]);
        } else {
            float m = mix[row * HEADS + h];
            float4 f0 = *(const float4*)fvp;
            float4 f1 = *(const float4*)(fvp + 4);
            float fvv[8] = {f0.x, f0.y, f0.z, f0.w, f1.x, f1.y, f1.z, f1.w};
            #pragma unroll
            for (int e = 0; e < 8; e++) vals[e] += m * (fvv[e] - vals[e]);
        }
        #pragma unroll
        for (int e = 0; e < 8; e++) {
            int d = d0 + e;
            *(short*)((char*)T + d * 128 + ((2 * n) ^ ((d & 7) << 4))) = (short)f2bf(vals[e]);
        }
    }
    __syncthreads();
    #pragma unroll
    for (int it = 0; it < 2; it++) {
        int flat = tid + 256 * it;
        int d = flat >> 3, nn0 = (flat & 7) * 8;
        uint4 v = *(const uint4*)((const char*)T + d * 128 + ((2 * nn0) ^ ((d & 7) << 4)));
        *(uint4*)(vtg + (size_t)(h * 64 + d) * NTOK + n0 + nn0) = v;
    }
}

// ---------------- MFMA flash attention: one block per q-tile, heavy-first --------
__global__ __launch_bounds__(256, 3) void attn_mfma_k(
        const unsigned short* __restrict__ Qbf, const unsigned short* __restrict__ Kbf,
        const unsigned short* __restrict__ Vtg, unsigned short* __restrict__ obf) {
    const int h = blockIdx.x;
    const int j = 31 - (int)blockIdx.y;
    const int tid = threadIdx.x;
    const int wv = tid >> 6, ln = tid & 63, g = ln >> 4, t = ln & 15;
    __shared__ __align__(16) short KsB[2][64 * 64];
    __shared__ __align__(16) short VtB[2][64 * 64];
    __shared__ __align__(16) short Plds[4 * 16 * 64];
    char* pw = (char*)(Plds + wv * 1024);

    const int sr = ln >> 3;
    const int scol = (ln & 7) ^ sr;                 // swizzle on global source
    const int sbyte0 = (wv * 16 + sr) * 128 + (ln & 7) * 16;
    const int sbyte1 = sbyte0 + 8 * 128;
    const unsigned short* kgl0 = Kbf + (size_t)(wv * 16 + sr) * DIM + h * 64 + scol * 8;
    const unsigned short* kgl1 = kgl0 + 8 * DIM;
    const unsigned short* vgl0 = Vtg + (size_t)(h * 64 + wv * 16 + sr) * NTOK + scol * 8;
    const unsigned short* vgl1 = vgl0 + 8 * NTOK;

    const int nch = ((j >> 1) + 1) * 2;
    const int qbase = j * 64;
    const unsigned short* qrow = Qbf + (size_t)(qbase + wv * 16 + t) * DIM + h * 64;
    bf16x8 qf0 = *(const bf16x8*)(qrow + 8 * g);
    bf16x8 qf1 = *(const bf16x8*)(qrow + 32 + 8 * g);
    f32x4 acc_o[4] = {};
    float mrun = -3.0e38f, lrun = 0.f;
    uint4 rk0 = *(const uint4*)kgl0;
    uint4 rk1 = *(const uint4*)kgl1;
    uint4 rv0 = *(const uint4*)vgl0;
    uint4 rv1 = *(const uint4*)vgl1;
    for (int kc = 0; kc < nch; kc++) {
        const int cur = kc & 1;
        *(uint4*)((char*)KsB[cur] + sbyte0) = rk0;
        *(uint4*)((char*)KsB[cur] + sbyte1) = rk1;
        *(uint4*)((char*)VtB[cur] + sbyte0) = rv0;
        *(uint4*)((char*)VtB[cur] + sbyte1) = rv1;
        if (kc + 1 < nch) {
            rk0 = *(const uint4*)(kgl0 + (size_t)(kc + 1) * 64 * DIM);
            rk1 = *(const uint4*)(kgl1 + (size_t)(kc + 1) * 64 * DIM);
            rv0 = *(const uint4*)(vgl0 + (kc + 1) * 64);
            rv1 = *(const uint4*)(vgl1 + (kc + 1) * 64);
        }
        __syncthreads();
        const char* Kc = (const char*)KsB[cur];
        const char* Vc = (const char*)VtB[cur];
        f32x4 accs[4] = {};
        #pragma unroll
        for (int kf = 0; kf < 4; kf++) {
            int row = kf * 16 + t;
            int kb0 = (g * 16) ^ ((row & 7) << 4);
            int kb1 = (64 + g * 16) ^ ((row & 7) << 4);
            bf16x8 k0 = *(const bf16x8*)(Kc + row * 128 + kb0);
            bf16x8 k1 = *(const bf16x8*)(Kc + row * 128 + kb1);
            accs[kf] = __builtin_amdgcn_mfma_f32_16x16x32_bf16(k0, qf0, accs[kf], 0, 0, 0);
            accs[kf] = __builtin_amdgcn_mfma_f32_16x16x32_bf16(k1, qf1, accs[kf], 0, 0, 0);
        }
        float pm = -3.0e38f;
        #pragma unroll
        for (int kf = 0; kf < 4; kf++)
            #pragma unroll
            for (int r = 0; r < 4; r++) pm = fmaxf(pm, accs[kf][r]);
        pm = fmaxf(pm, __shfl_xor(pm, 16));
        pm = fmaxf(pm, __shfl_xor(pm, 32));
        float mnew = fmaxf(mrun, pm);
        float corr = __expf(mrun - mnew);
        mrun = mnew;
        float psum = 0.f;
        #pragma unroll
        for (int kf = 0; kf < 4; kf++)
            #pragma unroll
            for (int r = 0; r < 4; r++) {
                float pv = __expf(accs[kf][r] - mnew);
                accs[kf][r] = pv;
                psum += pv;
            }
        psum += __shfl_xor(psum, 16);
        psum += __shfl_xor(psum, 32);
        lrun = lrun * corr + psum;
        #pragma unroll
        for (int kf = 0; kf < 4; kf++)
            #pragma unroll
            for (int rp = 0; rp < 4; rp += 2) {
                unsigned pv = pk2(accs[kf][rp], accs[kf][rp + 1]);
                int boff = (t * 128 + (16 * kf + 4 * g + rp) * 2) ^ ((t & 7) << 4);
                *(unsigned*)(pw + boff) = pv;
            }
        float cr[4];
        #pragma unroll
        for (int r = 0; r < 4; r++) cr[r] = __shfl(corr, g * 4 + r);
        #pragma unroll
        for (int ni = 0; ni < 4; ni++)
            #pragma unroll
            for (int r = 0; r < 4; r++) acc_o[ni][r] *= cr[r];
        #pragma unroll
        for (int ks = 0; ks < 2; ks++) {
            bf16x8 pa = *(const bf16x8*)(pw + ((t * 128 + 64 * ks + 16 * g) ^ ((t & 7) << 4)));
            #pragma unroll
            for (int ni = 0; ni < 4; ni++) {
                int row = ni * 16 + t;
                int vb = (64 * ks + 16 * g) ^ ((row & 7) << 4);
                bf16x8 vbf = *(const bf16x8*)(Vc + row * 128 + vb);
                acc_o[ni] = __builtin_amdgcn_mfma_f32_16x16x32_bf16(pa, vbf, acc_o[ni], 0, 0, 0);
            }
        }
    }
    float inv = 1.0f / lrun;
    float ir[4];
    #pragma unroll
    for (int r = 0; r < 4; r++) ir[r] = __shfl(inv, g * 4 + r);
    #pragma unroll
    for (int ni = 0; ni < 4; ni++)
        #pragma unroll
        for (int r = 0; r < 4; r++) {
            int row = qbase + wv * 16 + g * 4 + r;
            int col = h * 64 + ni * 16 + t;
            obf[(size_t)row * DIM + col] = f2bf(acc_o[ni][r] * ir[r]);
        }
}

// ---------------- driver ----------------------------------------------------------
extern "C" void kernel_launch(void* const* d_in, const int* in_sizes, int n_in,
                              void* d_out, int out_size, void* d_ws, size_t ws_size,
                              hipStream_t stream) {
    const float* tokens       = (const float*)d_in[0];
    const float* attn_norm_w  = (const float*)d_in[1];
    const float* w_qkv        = (const float*)d_in[2];
    const float* w_attn_out   = (const float*)d_in[3];
    const float* w_mix        = (const float*)d_in[4];
    const float* b_mix        = (const float*)d_in[5];
    const float* ff_norm_w    = (const float*)d_in[6];
    const float* w_ff_in      = (const float*)d_in[7];
    const float* b_ff_in      = (const float*)d_in[8];
    const float* w_ff_out     = (const float*)d_in[9];
    const float* b_ff_out     = (const float*)d_in[10];
    const float* final_norm_w = (const float*)d_in[11];

    char* p = (char*)d_ws;
    auto alloc = [&](size_t bytes) {
        char* r = p;
        p += (bytes + 255) & ~(size_t)255;
        return r;
    };
    short* wq_t  = (short*)alloc(4ull * 3072 * 1024 * 2);
    short* wo_t  = (short*)alloc(4ull * 1024 * 1024 * 2);
    short* wfa_t = (short*)alloc(4ull * FFNP * 1024 * 2);
    short* wfg_t = (short*)alloc(4ull * FFNP * 1024 * 2);
    short* wfo_t = (short*)alloc(4ull * 1024 * FFHP * 2);
    float* PART  = (float*)alloc((size_t)NTOK * 3072 * 4);  // union: qkv bf16 x2 | out bf16 x4
    float* X     = (float*)alloc((size_t)NTOK * DIM * 4);
    float* FV    = (float*)alloc((size_t)NTOK * DIM * 4);
    float* MIX   = (float*)alloc((size_t)NTOK * HEADS * 4);
    short* Hbf   = (short*)alloc((size_t)NTOK * DIM * 2);
    short* Obf   = (short*)alloc((size_t)NTOK * DIM * 2);
    short* ACTbf = (short*)alloc((size_t)NTOK * FFHP * 2);
    unsigned short* Qbf = (unsigned short*)alloc((size_t)NTOK * DIM * 2);
    unsigned short* Kbf = (unsigned short*)alloc((size_t)NTOK * DIM * 2);
    unsigned short* Vtg = (unsigned short*)alloc((size_t)HEADS * 64 * NTOK * 2);
    unsigned short* PARTq = (unsigned short*)PART;        // [2][NTOK][3072] bf16
    unsigned short* PARTb = (unsigned short*)PART;        // [4][NTOK][1024] bf16

    // weight convert+transpose (bf16, [N][K]), batched over layers via blockIdx.z
    wconv_k<<<dim3(48, 16, 4), 256, 0, stream>>>(
        w_qkv, wq_t, 1024, 3072, 0, 3072, 1024, 3072,
        (size_t)1024 * 3072, (size_t)3072 * 1024);
    wconv_k<<<dim3(16, 16, 4), 256, 0, stream>>>(
        w_attn_out, wo_t, 1024, 1024, 0, 1024, 1024, 1024,
        (size_t)1024 * 1024, (size_t)1024 * 1024);
    wconv_k<<<dim3(44, 16, 4), 256, 0, stream>>>(
        w_ff_in, wfa_t, 1024, FFH, 0, FF2, 1024, FFNP,
        (size_t)1024 * FF2, (size_t)FFNP * 1024);
    wconv_k<<<dim3(44, 16, 4), 256, 0, stream>>>(
        w_ff_in, wfg_t, 1024, FFH, FFH, FF2, 1024, FFNP,
        (size_t)1024 * FF2, (size_t)FFNP * 1024);
    wconv_k<<<dim3(16, 43, 4), 256, 0, stream>>>(
        w_ff_out, wfo_t, FFH, 1024, 0, 1024, FFHP, 1024,
        (size_t)FFH * 1024, (size_t)1024 * FFHP);

    hipMemcpyAsync(X, tokens, (size_t)NTOK * DIM * sizeof(float),
                   hipMemcpyDeviceToDevice, stream);
    // layer-0 attention norm (layers 1-3 get theirs fused into ff_out reduce)
    rmsnorm_k<<<NTOK, 256, 0, stream>>>(X, attn_norm_w, (unsigned short*)Hbf);

    for (int i = 0; i < DEPTH; i++) {
        gemm_splitk_k<2, 1><<<dim3(24, 16, 2), 256, 0, stream>>>(
            Hbf, wq_t + (size_t)i * 3072 * 1024, PARTq, 3072, 1024);
        qkvpost_k<<<dim3(16, 32), 256, 0, stream>>>(
            PARTq, Qbf, Kbf, FV, MIX, Vtg, i);
        attn_mfma_k<<<dim3(16, 32), 256, 0, stream>>>(Qbf, Kbf, Vtg,
                                                      (unsigned short*)Obf);
        gemm_splitk_k<4, 1><<<dim3(8, 16, 4), 256, 0, stream>>>(
            Obf, wo_t + (size_t)i * 1024 * 1024, PARTb, 1024, 1024);
        rmsnorm_red_k<4, 0><<<NTOK, 256, 0, stream>>>(
            X, PARTb, nullptr, ff_norm_w + (size_t)i * DIM, X, nullptr,
            (unsigned short*)Hbf, nullptr, nullptr, nullptr);
        gemm_swiglu_k<<<dim3(43, 16), 256, 0, stream>>>(
            Hbf, wfa_t + (size_t)i * FFNP * 1024, wfg_t + (size_t)i * FFNP * 1024,
            b_ff_in + (size_t)i * FF2, (unsigned short*)ACTbf);
        gemm_splitk_k<4, 1><<<dim3(8, 16, 4), 256, 0, stream>>>(
            ACTbf, wfo_t + (size_t)i * 1024 * FFHP, PARTb, 1024, FFHP);
        if (i < DEPTH - 1) {
            rmsnorm_red_k<4, 1><<<NTOK, 256, 0, stream>>>(
                X, PARTb, b_ff_out + (size_t)i * DIM, attn_norm_w + (size_t)(i + 1) * DIM,
                X, nullptr, (unsigned short*)Hbf,
                w_mix + (size_t)(i + 1) * DIM * HEADS, b_mix + (size_t)(i + 1) * HEADS,
                MIX);
        } else {
            rmsnorm_red_k<4, 0><<<NTOK, 256, 0, stream>>>(
                X, PARTb, b_ff_out + (size_t)i * DIM, final_norm_w,
                nullptr, (float*)d_out, nullptr, nullptr, nullptr, nullptr);
        }
    }
}